// Round 1
// baseline (1653.926 us; speedup 1.0000x reference)
//
#include <hip/hip_runtime.h>

typedef __attribute__((ext_vector_type(4))) float f32x4;
typedef __attribute__((ext_vector_type(8))) short s16x8;
typedef unsigned short u16;
typedef unsigned int u32;

// ---------- helpers ----------
__device__ __forceinline__ u16 f2bf(float f){
  u32 u = __builtin_bit_cast(u32, f);
  u += 0x7fffu + ((u >> 16) & 1u);          // RNE
  return (u16)(u >> 16);
}
__device__ __forceinline__ float gelu_exact(float x){
  return 0.5f * x * (1.0f + erff(x * 0.70710678118654752f));
}
__device__ __forceinline__ float sigmoidf_(float x){
  return 1.0f / (1.0f + expf(-x));
}

// 256-thread block reductions (4 waves)
__device__ __forceinline__ float blk_sum(float v, float* red){
  #pragma unroll
  for (int off = 32; off; off >>= 1) v += __shfl_xor(v, off, 64);
  int t = threadIdx.x;
  if ((t & 63) == 0) red[t >> 6] = v;
  __syncthreads();
  float r = red[0] + red[1] + red[2] + red[3];
  __syncthreads();
  return r;
}
__device__ __forceinline__ float blk_max(float v, float* red){
  #pragma unroll
  for (int off = 32; off; off >>= 1) v = fmaxf(v, __shfl_xor(v, off, 64));
  int t = threadIdx.x;
  if ((t & 63) == 0) red[t >> 6] = v;
  __syncthreads();
  float r = fmaxf(fmaxf(red[0], red[1]), fmaxf(red[2], red[3]));
  __syncthreads();
  return r;
}

// ---------- transpose + elementwise op (fp32 in -> bf16/fp32 out, [R][C] -> [C][R]) ----------
enum { OPC_CAST = 0, OPC_SIGM05 = 1, OPC_SIG2M1 = 2 };

template<int OP, typename OutT>
__global__ __launch_bounds__(256) void transpose_op(const float* __restrict__ in,
                                                    OutT* __restrict__ out, int R, int C){
  __shared__ float tile[64][65];
  const int tc = blockIdx.x, tr = blockIdx.y;
  const int c = threadIdx.x & 63, r4 = threadIdx.x >> 6;
  #pragma unroll
  for (int i = 0; i < 16; i++){
    int r = r4 * 16 + i;
    float v = in[(size_t)(tr * 64 + r) * C + tc * 64 + c];
    if (OP == OPC_SIGM05)      v = sigmoidf_(v) - 0.5f;
    else if (OP == OPC_SIG2M1) v = 2.0f * sigmoidf_(v) - 1.0f;
    tile[r][c] = v;
  }
  __syncthreads();
  #pragma unroll
  for (int i = 0; i < 16; i++){
    int r = r4 * 16 + i;
    float v = tile[c][r];
    size_t o = (size_t)(tc * 64 + r) * R + tr * 64 + c;
    if constexpr (sizeof(OutT) == 2) out[o] = f2bf(v);
    else                             out[o] = v;
  }
}

// ---------- sinkhorn ----------
__global__ __launch_bounds__(256) void sk_softmax_k(const float* __restrict__ raw,
                                                    float* __restrict__ A0){
  __shared__ float red[4];
  const int row = blockIdx.x, t = threadIdx.x;
  const float4 v = *(const float4*)(raw + (size_t)row * 1024 + t * 4);
  float mx = fmaxf(fmaxf(v.x, v.y), fmaxf(v.z, v.w));
  mx = blk_max(mx, red);
  float e0 = expf(v.x - mx), e1 = expf(v.y - mx), e2 = expf(v.z - mx), e3 = expf(v.w - mx);
  float s = blk_sum(e0 + e1 + e2 + e3, red);
  float sc = 1024.0f / s;
  float4 o = { e0 * sc, e1 * sc, e2 * sc, e3 * sc };
  *(float4*)(A0 + (size_t)row * 1024 + t * 4) = o;
}

__global__ __launch_bounds__(256) void sk_init(float* p, int n){
  int i = blockIdx.x * 256 + threadIdx.x;
  if (i < n) p[i] = 1.0f;
}

// vupd[row] = vupd[row] / (vupd[row]*dot(Am[row,:], vin) + 1e-8)
__global__ __launch_bounds__(256) void sk_pass(const float* __restrict__ Am,
                                               const float* __restrict__ vin,
                                               float* __restrict__ vupd){
  __shared__ float red[4];
  const int row = blockIdx.x, t = threadIdx.x;
  const float4 a = *(const float4*)(Am + (size_t)row * 1024 + t * 4);
  const float4 b = *(const float4*)(vin + t * 4);
  float d = a.x * b.x + a.y * b.y + a.z * b.z + a.w * b.w;
  d = blk_sum(d, red);
  if (t == 0){ float rv = vupd[row]; vupd[row] = rv / (rv * d + 1e-8f); }
}

// HresT[e][d] = bf16(r[d] * A0T[e][d] * c[e])
__global__ __launch_bounds__(256) void sk_mat(const float* __restrict__ A0T,
                                              const float* __restrict__ r,
                                              const float* __restrict__ c,
                                              u16* __restrict__ HresT){
  const int e = blockIdx.x, t = threadIdx.x;
  const float ce = c[e];
  const float4 a  = *(const float4*)(A0T + (size_t)e * 1024 + t * 4);
  const float4 rv = *(const float4*)(r + t * 4);
  ushort4 o;
  o.x = f2bf(a.x * rv.x * ce); o.y = f2bf(a.y * rv.y * ce);
  o.z = f2bf(a.z * rv.z * ce); o.w = f2bf(a.w * rv.w * ce);
  *(ushort4*)(HresT + (size_t)e * 1024 + t * 4) = o;
}

// ---------- layernorms ----------
__global__ __launch_bounds__(256) void ln1_kernel(const float* __restrict__ x,
    const float* __restrict__ g, const float* __restrict__ b,
    u16* __restrict__ xn, u16* __restrict__ xbf, float* __restrict__ sOut){
  __shared__ float red[4];
  const int row = blockIdx.x, t = threadIdx.x;
  const float4 v = *(const float4*)(x + (size_t)row * 1024 + t * 4);
  float mu = blk_sum(v.x + v.y + v.z + v.w, red) * (1.0f / 1024.0f);
  float d0 = v.x - mu, d1 = v.y - mu, d2 = v.z - mu, d3 = v.w - mu;
  float var = blk_sum(d0 * d0 + d1 * d1 + d2 * d2 + d3 * d3, red) * (1.0f / 1024.0f);
  float rstd = rsqrtf(var + 1e-5f);
  const float4 gv = *(const float4*)(g + t * 4);
  const float4 bv = *(const float4*)(b + t * 4);
  float y0 = d0 * rstd * gv.x + bv.x;
  float y1 = d1 * rstd * gv.y + bv.y;
  float y2 = d2 * rstd * gv.z + bv.z;
  float y3 = d3 * rstd * gv.w + bv.w;
  float ss = blk_sum(y0 + y1 + y2 + y3, red);   // fp32 row-sum of xn (for H_pre 0.5-part)
  if (t == 0) sOut[row] = ss;
  ushort4 o;  o.x = f2bf(y0);  o.y = f2bf(y1);  o.z = f2bf(y2);  o.w = f2bf(y3);
  *(ushort4*)(xn + (size_t)row * 1024 + t * 4) = o;
  ushort4 xo; xo.x = f2bf(v.x); xo.y = f2bf(v.y); xo.z = f2bf(v.z); xo.w = f2bf(v.w);
  *(ushort4*)(xbf + (size_t)row * 1024 + t * 4) = xo;
}

__global__ __launch_bounds__(256) void ln2_kernel(const float* __restrict__ y,
    const float* __restrict__ g, const float* __restrict__ b, float* __restrict__ out){
  __shared__ float red[4];
  const int row = blockIdx.x, t = threadIdx.x;
  const float4 v = *(const float4*)(y + (size_t)row * 1024 + t * 4);
  float mu = blk_sum(v.x + v.y + v.z + v.w, red) * (1.0f / 1024.0f);
  float d0 = v.x - mu, d1 = v.y - mu, d2 = v.z - mu, d3 = v.w - mu;
  float var = blk_sum(d0 * d0 + d1 * d1 + d2 * d2 + d3 * d3, red) * (1.0f / 1024.0f);
  float rstd = rsqrtf(var + 1e-5f);
  const float4 gv = *(const float4*)(g + t * 4);
  const float4 bv = *(const float4*)(b + t * 4);
  float4 o = { d0 * rstd * gv.x + bv.x, d1 * rstd * gv.y + bv.y,
               d2 * rstd * gv.z + bv.z, d3 * rstd * gv.w + bv.w };
  *(float4*)(out + (size_t)row * 1024 + t * 4) = o;
}

// ---------- GEMM: C[M,N] = A[M,K](bf16) * B (given as BT[N,K] bf16), fp32 accum ----------
enum { EPI_SBIAS = 0, EPI_GELU = 1, EPI_F32 = 2, EPI_ADDF32 = 3 };

__device__ __forceinline__ void gload16(const void* g, void* l){
  __builtin_amdgcn_global_load_lds((const __attribute__((address_space(1))) u32*)g,
                                   (__attribute__((address_space(3))) u32*)l, 16, 0, 0);
}

template<int EPI>
__global__ __launch_bounds__(256, 2) void gemm_bt(const u16* __restrict__ A,
    const u16* __restrict__ BT, int M, int N, int K,
    u16* __restrict__ obf, float* __restrict__ ofp,
    const float* __restrict__ bcol, const float* __restrict__ brow){
  __shared__ u16 lsA[128 * 64];
  __shared__ u16 lsB[128 * 64];
  const int t = threadIdx.x;
  const int lane = t & 63;
  const int wave = t >> 6;
  const int br = blockIdx.y * 128;
  const int bc = blockIdx.x * 128;
  const int wr = (wave >> 1) * 64;
  const int wc = (wave & 1) * 64;

  f32x4 acc[4][4] = {};

  // staging descriptors: 1024 16B-chunks per tile; swizzle: logical chunk = phys ^ (row&7)
  size_t aoff[4], boff[4];
  u16 *adst[4], *bdst[4];
  #pragma unroll
  for (int i = 0; i < 4; i++){
    int p = i * 256 + t;
    int row = p >> 3;
    int lc = (p & 7) ^ (row & 7);
    aoff[i] = (size_t)(br + row) * K + lc * 8;
    boff[i] = (size_t)(bc + row) * K + lc * 8;
    adst[i] = lsA + p * 8;
    bdst[i] = lsB + p * 8;
  }

  const int fr = lane & 15;
  const int colb0 = (lane >> 4) * 16;      // byte offset of this lane's 8 k-values

  for (int kt = 0; kt < K; kt += 64){
    __syncthreads();
    #pragma unroll
    for (int i = 0; i < 4; i++) gload16(A + aoff[i] + kt, adst[i]);
    #pragma unroll
    for (int i = 0; i < 4; i++) gload16(BT + boff[i] + kt, bdst[i]);
    __syncthreads();
    #pragma unroll
    for (int kk = 0; kk < 2; kk++){
      s16x8 af[4], bfr[4];
      #pragma unroll
      for (int m = 0; m < 4; m++){
        int row = wr + m * 16 + fr;
        int off = (row * 128 + kk * 64 + colb0) ^ ((row & 7) << 4);
        af[m] = *(const s16x8*)((const char*)lsA + off);
      }
      #pragma unroll
      for (int n = 0; n < 4; n++){
        int row = wc + n * 16 + fr;
        int off = (row * 128 + kk * 64 + colb0) ^ ((row & 7) << 4);
        bfr[n] = *(const s16x8*)((const char*)lsB + off);
      }
      #pragma unroll
      for (int m = 0; m < 4; m++)
        #pragma unroll
        for (int n = 0; n < 4; n++)
          acc[m][n] = __builtin_amdgcn_mfma_f32_16x16x32_bf16(af[m], bfr[n], acc[m][n], 0, 0, 0);
    }
  }

  const int orow = br + wr + ((lane >> 4) * 4);
  const int ocol = bc + wc + (lane & 15);
  #pragma unroll
  for (int m = 0; m < 4; m++){
    #pragma unroll
    for (int n = 0; n < 4; n++){
      #pragma unroll
      for (int r = 0; r < 4; r++){
        int gr = orow + m * 16 + r;
        int gc = ocol + n * 16;
        float v = acc[m][n][r];
        size_t idx = (size_t)gr * N + gc;
        if (EPI == EPI_SBIAS)      obf[idx] = f2bf(v + 0.5f * brow[gr]);
        else if (EPI == EPI_GELU)  obf[idx] = f2bf(gelu_exact(v + bcol[gc]));
        else if (EPI == EPI_F32)   ofp[idx] = v;
        else                       ofp[idx] += v;
      }
    }
  }
}

// ---------- launch ----------
extern "C" void kernel_launch(void* const* d_in, const int* in_sizes, int n_in,
                              void* d_out, int out_size, void* d_ws, size_t ws_size,
                              hipStream_t stream){
  const float* x      = (const float*)d_in[0];
  const float* HpreR  = (const float*)d_in[1];
  const float* HpostR = (const float*)d_in[2];
  const float* HresR  = (const float*)d_in[3];
  const float* W1     = (const float*)d_in[4];
  const float* b1     = (const float*)d_in[5];
  const float* W2     = (const float*)d_in[6];
  const float* b2     = (const float*)d_in[7];
  const float* gpre   = (const float*)d_in[8];
  const float* bpre   = (const float*)d_in[9];
  const float* gpost  = (const float*)d_in[10];
  const float* bpost  = (const float*)d_in[11];
  float* out = (float*)d_out;
  char* w = (char*)d_ws;
  constexpr size_t MBc = 1ull << 20;

  u16*   W1T    = (u16*)(w + 0);          // [8192][4096] 64MB
  u16*   W2T    = (u16*)(w + 64 * MBc);   // [4096][8192] 64MB
  u16*   DPRET  = (u16*)(w + 128 * MBc);  // [4096][1024] 8MB  = (sigmoid(Hpre)-0.5)^T
  u16*   DPOSTT = (u16*)(w + 136 * MBc);  // [1024][4096] 8MB  = (2sigmoid(Hpost)-1)^T
  u16*   HREST  = (u16*)(w + 144 * MBc);  // [1024][1024] 2MB
  u16*   XN     = (u16*)(w + 146 * MBc);  // [8192][1024] 16MB
  u16*   XBF    = (u16*)(w + 162 * MBc);  // [8192][1024] 16MB
  float* S      = (float*)(w + 178 * MBc);// [8192]
  float* A0     = (float*)(w + 179 * MBc);// [1024][1024] fp32 4MB
  float* A0T    = (float*)(w + 183 * MBc);// 4MB
  float* Rv     = (float*)(w + 187 * MBc);// [1024]
  float* Cv     = Rv + 1024;              // [1024]
  u16*   XEXP   = (u16*)(w + 188 * MBc);  // [8192][4096] 64MB (reused chunkwise as h2)
  u16*   H1     = (u16*)(w + 252 * MBc);  // [2048][8192] 32MB chunk buffer
  float* VAR    = (float*)(w + 252 * MBc);// [8192][1024] fp32 32MB (after h1 dead)

  dim3 blk(256);

  // weight precompute (transposed to [N][K] for the B^T GEMM)
  transpose_op<OPC_CAST,  u16><<<dim3(128, 64), blk, 0, stream>>>(W1, W1T, 4096, 8192);
  transpose_op<OPC_CAST,  u16><<<dim3(64, 128), blk, 0, stream>>>(W2, W2T, 8192, 4096);
  transpose_op<OPC_SIGM05,u16><<<dim3(64, 16),  blk, 0, stream>>>(HpreR, DPRET, 1024, 4096);
  transpose_op<OPC_SIG2M1,u16><<<dim3(16, 64),  blk, 0, stream>>>(HpostR, DPOSTT, 4096, 1024);

  // sinkhorn (scaling-vector form; exact incl. eps placement)
  sk_softmax_k<<<1024, blk, 0, stream>>>(HresR, A0);
  transpose_op<OPC_CAST, float><<<dim3(16, 16), blk, 0, stream>>>(A0, A0T, 1024, 1024);
  sk_init<<<8, blk, 0, stream>>>(Rv, 2048);
  for (int i = 0; i < 20; i++){
    sk_pass<<<1024, blk, 0, stream>>>(A0,  Cv, Rv);   // row normalize
    sk_pass<<<1024, blk, 0, stream>>>(A0T, Rv, Cv);   // col normalize
  }
  sk_mat<<<1024, blk, 0, stream>>>(A0T, Rv, Cv, HREST);

  // pre-LN (+ fp32 row sums of xn, + bf16 copy of raw x)
  ln1_kernel<<<8192, blk, 0, stream>>>(x, gpre, bpre, XN, XBF, S);

  // G1: x_exp = xn @ (Hpre-0.5)  + 0.5*s   -> bf16 [8192][4096]
  gemm_bt<EPI_SBIAS><<<dim3(32, 64), blk, 0, stream>>>(XN, DPRET, 8192, 4096, 1024,
                                                       XEXP, nullptr, nullptr, S);
  // G2/G3 in 4 row-chunks of 2048 (h1 chunk buffer; h2 overwrites x_exp chunk)
  for (int c0 = 0; c0 < 4; c0++){
    const u16* ax = XEXP + (size_t)c0 * 2048 * 4096;
    u16* h2c      = XEXP + (size_t)c0 * 2048 * 4096;
    gemm_bt<EPI_GELU><<<dim3(64, 16), blk, 0, stream>>>(ax, W1T, 2048, 8192, 4096,
                                                        H1, nullptr, b1, nullptr);
    gemm_bt<EPI_GELU><<<dim3(32, 16), blk, 0, stream>>>(H1, W2T, 2048, 4096, 8192,
                                                        h2c, nullptr, b2, nullptr);
  }
  // G4: var = h2 @ (2sigmoid(Hpost)-1)   (the +1*rowsum constant cancels in final LN)
  gemm_bt<EPI_F32><<<dim3(8, 64), blk, 0, stream>>>(XEXP, DPOSTT, 8192, 1024, 4096,
                                                    nullptr, VAR, nullptr, nullptr);
  // G5: VAR += x @ Hres
  gemm_bt<EPI_ADDF32><<<dim3(8, 64), blk, 0, stream>>>(XBF, HREST, 8192, 1024, 1024,
                                                       nullptr, VAR, nullptr, nullptr);
  // final LN -> fp32 out
  ln2_kernel<<<8192, blk, 0, stream>>>(VAR, gpost, bpost, out);
}

// Round 2
// 1587.445 us; speedup vs baseline: 1.0419x; 1.0419x over previous
//
#include <hip/hip_runtime.h>

typedef __attribute__((ext_vector_type(4))) float f32x4;
typedef __attribute__((ext_vector_type(8))) short s16x8;
typedef unsigned short u16;
typedef unsigned int u32;

// ---------- helpers ----------
__device__ __forceinline__ u16 f2bf(float f){
  u32 u = __builtin_bit_cast(u32, f);
  u += 0x7fffu + ((u >> 16) & 1u);          // RNE
  return (u16)(u >> 16);
}
__device__ __forceinline__ float gelu_exact(float x){
  return 0.5f * x * (1.0f + erff(x * 0.70710678118654752f));
}
__device__ __forceinline__ float sigmoidf_(float x){
  return 1.0f / (1.0f + expf(-x));
}

// 256-thread block reductions (4 waves)
__device__ __forceinline__ float blk_sum(float v, float* red){
  #pragma unroll
  for (int off = 32; off; off >>= 1) v += __shfl_xor(v, off, 64);
  int t = threadIdx.x;
  if ((t & 63) == 0) red[t >> 6] = v;
  __syncthreads();
  float r = red[0] + red[1] + red[2] + red[3];
  __syncthreads();
  return r;
}
__device__ __forceinline__ float blk_max(float v, float* red){
  #pragma unroll
  for (int off = 32; off; off >>= 1) v = fmaxf(v, __shfl_xor(v, off, 64));
  int t = threadIdx.x;
  if ((t & 63) == 0) red[t >> 6] = v;
  __syncthreads();
  float r = fmaxf(fmaxf(red[0], red[1]), fmaxf(red[2], red[3]));
  __syncthreads();
  return r;
}

// ---------- transpose + elementwise op (fp32 in -> bf16/fp32 out, [R][C] -> [C][R]) ----------
enum { OPC_CAST = 0, OPC_SIGM05 = 1, OPC_SIG2M1 = 2 };

template<int OP, typename OutT>
__global__ __launch_bounds__(256) void transpose_op(const float* __restrict__ in,
                                                    OutT* __restrict__ out, int R, int C){
  __shared__ float tile[64][65];
  const int tc = blockIdx.x, tr = blockIdx.y;
  const int c = threadIdx.x & 63, r4 = threadIdx.x >> 6;
  #pragma unroll
  for (int i = 0; i < 16; i++){
    int r = r4 * 16 + i;
    float v = in[(size_t)(tr * 64 + r) * C + tc * 64 + c];
    if (OP == OPC_SIGM05)      v = sigmoidf_(v) - 0.5f;
    else if (OP == OPC_SIG2M1) v = 2.0f * sigmoidf_(v) - 1.0f;
    tile[r][c] = v;
  }
  __syncthreads();
  #pragma unroll
  for (int i = 0; i < 16; i++){
    int r = r4 * 16 + i;
    float v = tile[c][r];
    size_t o = (size_t)(tc * 64 + r) * R + tr * 64 + c;
    if constexpr (sizeof(OutT) == 2) out[o] = f2bf(v);
    else                             out[o] = v;
  }
}

// ---------- sinkhorn ----------
__global__ __launch_bounds__(256) void sk_softmax_k(const float* __restrict__ raw,
                                                    float* __restrict__ A0){
  __shared__ float red[4];
  const int row = blockIdx.x, t = threadIdx.x;
  const float4 v = *(const float4*)(raw + (size_t)row * 1024 + t * 4);
  float mx = fmaxf(fmaxf(v.x, v.y), fmaxf(v.z, v.w));
  mx = blk_max(mx, red);
  float e0 = expf(v.x - mx), e1 = expf(v.y - mx), e2 = expf(v.z - mx), e3 = expf(v.w - mx);
  float s = blk_sum(e0 + e1 + e2 + e3, red);
  float sc = 1024.0f / s;
  float4 o = { e0 * sc, e1 * sc, e2 * sc, e3 * sc };
  *(float4*)(A0 + (size_t)row * 1024 + t * 4) = o;
}

__global__ __launch_bounds__(256) void sk_init(float* p, int n){
  int i = blockIdx.x * 256 + threadIdx.x;
  if (i < n) p[i] = 1.0f;
}

// vupd[row] = vupd[row] / (vupd[row]*dot(Am[row,:], vin) + 1e-8)
__global__ __launch_bounds__(256) void sk_pass(const float* __restrict__ Am,
                                               const float* __restrict__ vin,
                                               float* __restrict__ vupd){
  __shared__ float red[4];
  const int row = blockIdx.x, t = threadIdx.x;
  const float4 a = *(const float4*)(Am + (size_t)row * 1024 + t * 4);
  const float4 b = *(const float4*)(vin + t * 4);
  float d = a.x * b.x + a.y * b.y + a.z * b.z + a.w * b.w;
  d = blk_sum(d, red);
  if (t == 0){ float rv = vupd[row]; vupd[row] = rv / (rv * d + 1e-8f); }
}

// HresT[e][d] = bf16(r[d] * A0T[e][d] * c[e])
__global__ __launch_bounds__(256) void sk_mat(const float* __restrict__ A0T,
                                              const float* __restrict__ r,
                                              const float* __restrict__ c,
                                              u16* __restrict__ HresT){
  const int e = blockIdx.x, t = threadIdx.x;
  const float ce = c[e];
  const float4 a  = *(const float4*)(A0T + (size_t)e * 1024 + t * 4);
  const float4 rv = *(const float4*)(r + t * 4);
  ushort4 o;
  o.x = f2bf(a.x * rv.x * ce); o.y = f2bf(a.y * rv.y * ce);
  o.z = f2bf(a.z * rv.z * ce); o.w = f2bf(a.w * rv.w * ce);
  *(ushort4*)(HresT + (size_t)e * 1024 + t * 4) = o;
}

// ---------- layernorms ----------
__global__ __launch_bounds__(256) void ln1_kernel(const float* __restrict__ x,
    const float* __restrict__ g, const float* __restrict__ b,
    u16* __restrict__ xn, u16* __restrict__ xbf, float* __restrict__ sOut){
  __shared__ float red[4];
  const int row = blockIdx.x, t = threadIdx.x;
  const float4 v = *(const float4*)(x + (size_t)row * 1024 + t * 4);
  float mu = blk_sum(v.x + v.y + v.z + v.w, red) * (1.0f / 1024.0f);
  float d0 = v.x - mu, d1 = v.y - mu, d2 = v.z - mu, d3 = v.w - mu;
  float var = blk_sum(d0 * d0 + d1 * d1 + d2 * d2 + d3 * d3, red) * (1.0f / 1024.0f);
  float rstd = rsqrtf(var + 1e-5f);
  const float4 gv = *(const float4*)(g + t * 4);
  const float4 bv = *(const float4*)(b + t * 4);
  float y0 = d0 * rstd * gv.x + bv.x;
  float y1 = d1 * rstd * gv.y + bv.y;
  float y2 = d2 * rstd * gv.z + bv.z;
  float y3 = d3 * rstd * gv.w + bv.w;
  float ss = blk_sum(y0 + y1 + y2 + y3, red);   // fp32 row-sum of xn (for H_pre 0.5-part)
  if (t == 0) sOut[row] = ss;
  ushort4 o;  o.x = f2bf(y0);  o.y = f2bf(y1);  o.z = f2bf(y2);  o.w = f2bf(y3);
  *(ushort4*)(xn + (size_t)row * 1024 + t * 4) = o;
  ushort4 xo; xo.x = f2bf(v.x); xo.y = f2bf(v.y); xo.z = f2bf(v.z); xo.w = f2bf(v.w);
  *(ushort4*)(xbf + (size_t)row * 1024 + t * 4) = xo;
}

__global__ __launch_bounds__(256) void ln2_kernel(const float* __restrict__ y,
    const float* __restrict__ g, const float* __restrict__ b, float* __restrict__ out){
  __shared__ float red[4];
  const int row = blockIdx.x, t = threadIdx.x;
  const float4 v = *(const float4*)(y + (size_t)row * 1024 + t * 4);
  float mu = blk_sum(v.x + v.y + v.z + v.w, red) * (1.0f / 1024.0f);
  float d0 = v.x - mu, d1 = v.y - mu, d2 = v.z - mu, d3 = v.w - mu;
  float var = blk_sum(d0 * d0 + d1 * d1 + d2 * d2 + d3 * d3, red) * (1.0f / 1024.0f);
  float rstd = rsqrtf(var + 1e-5f);
  const float4 gv = *(const float4*)(g + t * 4);
  const float4 bv = *(const float4*)(b + t * 4);
  float4 o = { d0 * rstd * gv.x + bv.x, d1 * rstd * gv.y + bv.y,
               d2 * rstd * gv.z + bv.z, d3 * rstd * gv.w + bv.w };
  *(float4*)(out + (size_t)row * 1024 + t * 4) = o;
}

enum { EPI_SBIAS = 0, EPI_GELU = 1, EPI_F32 = 2, EPI_ADDF32 = 3 };

__device__ __forceinline__ void gload16(const void* g, void* l){
  __builtin_amdgcn_global_load_lds((const __attribute__((address_space(1))) u32*)g,
                                   (__attribute__((address_space(3))) u32*)l, 16, 0, 0);
}

// ---------- 256x256 8-phase GEMM: C[M,N] = A[M,K](bf16) * BT[N,K](bf16), fp32 accum ----
// 512 threads = 8 waves (2Mx4N), per-wave 128x64 output, BK=64, LDS 128KB dbuf,
// raw s_barrier + counted vmcnt(8) (never 0 in main loop), XOR-16B row swizzle.
template<int EPI>
__global__ __launch_bounds__(512, 2) void gemm8(const u16* __restrict__ A,
    const u16* __restrict__ BT, int K, int ldc,
    u16* __restrict__ obf, float* __restrict__ ofp,
    const float* __restrict__ bcol, const float* __restrict__ brow){
  __shared__ __align__(16) u16 lsA[2 * 256 * 64];
  __shared__ __align__(16) u16 lsB[2 * 256 * 64];
  const int tid = threadIdx.x;
  const int lane = tid & 63;
  const int wave = tid >> 6;

  // bijective XCD swizzle (all grids here are %8==0)
  const u32 gx = gridDim.x;
  const u32 nwg = gx * gridDim.y;
  const u32 orig = blockIdx.y * gx + blockIdx.x;
  const u32 swzid = (orig & 7) * (nwg >> 3) + (orig >> 3);
  const int br = (int)(swzid / gx) * 256;
  const int bc = (int)(swzid % gx) * 256;

  const int wr  = (wave >> 2) * 128;   // wave row block
  const int wc_ = (wave & 3) * 64;     // wave col block

  // ds_read swizzled bases
  const int fr = lane & 15;
  const int colb0 = (lane >> 4) * 16;
  const int swz = colb0 ^ ((fr & 7) << 4);
  const int sA0 = (wr + fr) * 128 + swz;
  const int sA1 = (wr + fr) * 128 + (swz ^ 64);
  const int sB0 = (wc_ + fr) * 128 + swz;
  const int sB1 = (wc_ + fr) * 128 + (swz ^ 64);
  const char* lsAc = (const char*)lsA;
  const char* lsBc = (const char*)lsB;

  // staging: per thread one 16B chunk per 8KB round; 8 rounds/tile.
  // rounds a0..a3 = A rows {0-63,128-191,64-127,192-255}
  // rounds b0..b3 = B rows {0-31|64-95, 128-159|192-223, 32-63|96-127, 160-191|224-255}
  const int r = tid >> 3, s = tid & 7;
  const int lc8 = ((s ^ (r & 7)) * 8);
  const int rb_ = (r & 31) + ((r >> 5) << 6);
  const int rA[4] = { r, r + 128, r + 64, r + 192 };
  const int rB[4] = { rb_, rb_ + 128, rb_ + 32, rb_ + 160 };
  u32 srcA[4], srcB[4], dstA[4], dstB[4];
  #pragma unroll
  for (int i = 0; i < 4; i++){
    srcA[i] = (u32)(br + rA[i]) * (u32)K + (u32)lc8;
    srcB[i] = (u32)(bc + rB[i]) * (u32)K + (u32)lc8;
    dstA[i] = (u32)(rA[i] * 128 + s * 16);
    dstB[i] = (u32)(rB[i] * 128 + s * 16);
  }
  auto stA = [&](int i, u32 koff, u32 pb){ gload16(A  + srcA[i] + koff, (char*)lsA + pb + dstA[i]); };
  auto stB = [&](int i, u32 koff, u32 pb){ gload16(BT + srcB[i] + koff, (char*)lsB + pb + dstB[i]); };

  const int NT = K >> 6;
  f32x4 acc[8][4] = {};

  // prologue: stage tile0 -> buf0, tile1 -> buf1; wait tile0
  #pragma unroll
  for (int i = 0; i < 4; i++){ stA(i, 0, 0); stB(i, 0, 0); }
  #pragma unroll
  for (int i = 0; i < 4; i++){ stA(i, 64, 32768u); stB(i, 64, 32768u); }
  asm volatile("s_waitcnt vmcnt(8)" ::: "memory");
  __builtin_amdgcn_sched_barrier(0);
  __builtin_amdgcn_s_barrier();

  u32 koff = 128;
  for (int t = 0; t < NT; ++t){
    const u32 pb = (t & 1) ? 32768u : 0u;
    const bool st = (t + 2) < NT;
    s16x8 a0[4][2], a1[4][2], b0[2][2], b1[2][2];

    // ---- phase 0: read A-h0 (8) + B-h0 (4); MFMA Q(mh0 x nh0)
    #pragma unroll
    for (int m = 0; m < 4; m++){
      a0[m][0] = *(const s16x8*)(lsAc + pb + sA0 + m * 2048);
      a0[m][1] = *(const s16x8*)(lsAc + pb + sA1 + m * 2048);
    }
    #pragma unroll
    for (int n = 0; n < 2; n++){
      b0[n][0] = *(const s16x8*)(lsBc + pb + sB0 + n * 2048);
      b0[n][1] = *(const s16x8*)(lsBc + pb + sB1 + n * 2048);
    }
    __builtin_amdgcn_sched_barrier(0);
    __builtin_amdgcn_s_barrier();
    asm volatile("s_waitcnt lgkmcnt(0)" ::: "memory");
    __builtin_amdgcn_sched_barrier(0);
    __builtin_amdgcn_s_setprio(1);
    #pragma unroll
    for (int kk = 0; kk < 2; kk++)
      #pragma unroll
      for (int m = 0; m < 4; m++)
        #pragma unroll
        for (int n = 0; n < 2; n++)
          acc[m][n] = __builtin_amdgcn_mfma_f32_16x16x32_bf16(a0[m][kk], b0[n][kk], acc[m][n], 0, 0, 0);
    __builtin_amdgcn_s_setprio(0);
    __builtin_amdgcn_sched_barrier(0);
    __builtin_amdgcn_s_barrier();

    // ---- phase 1: read B-h1 (4); stage t+2 A-ht0 (rows read in p0); MFMA Q(mh0 x nh1)
    #pragma unroll
    for (int n = 0; n < 2; n++){
      b1[n][0] = *(const s16x8*)(lsBc + pb + sB0 + (n + 2) * 2048);
      b1[n][1] = *(const s16x8*)(lsBc + pb + sB1 + (n + 2) * 2048);
    }
    if (st){ stA(0, koff, pb); stA(1, koff, pb); }
    __builtin_amdgcn_sched_barrier(0);
    __builtin_amdgcn_s_barrier();
    asm volatile("s_waitcnt lgkmcnt(0)" ::: "memory");
    __builtin_amdgcn_sched_barrier(0);
    __builtin_amdgcn_s_setprio(1);
    #pragma unroll
    for (int kk = 0; kk < 2; kk++)
      #pragma unroll
      for (int m = 0; m < 4; m++)
        #pragma unroll
        for (int n = 0; n < 2; n++)
          acc[m][n + 2] = __builtin_amdgcn_mfma_f32_16x16x32_bf16(a0[m][kk], b1[n][kk], acc[m][n + 2], 0, 0, 0);
    __builtin_amdgcn_s_setprio(0);
    __builtin_amdgcn_sched_barrier(0);
    __builtin_amdgcn_s_barrier();

    // ---- phase 2: read A-h1 (8); stage t+2 B-ht0 (rows read in p0); MFMA Q(mh1 x nh1)
    #pragma unroll
    for (int m = 0; m < 4; m++){
      a1[m][0] = *(const s16x8*)(lsAc + pb + sA0 + (m + 4) * 2048);
      a1[m][1] = *(const s16x8*)(lsAc + pb + sA1 + (m + 4) * 2048);
    }
    if (st){ stB(0, koff, pb); stB(1, koff, pb); }
    __builtin_amdgcn_sched_barrier(0);
    __builtin_amdgcn_s_barrier();
    asm volatile("s_waitcnt lgkmcnt(0)" ::: "memory");
    __builtin_amdgcn_sched_barrier(0);
    __builtin_amdgcn_s_setprio(1);
    #pragma unroll
    for (int kk = 0; kk < 2; kk++)
      #pragma unroll
      for (int m = 0; m < 4; m++)
        #pragma unroll
        for (int n = 0; n < 2; n++)
          acc[m + 4][n + 2] = __builtin_amdgcn_mfma_f32_16x16x32_bf16(a1[m][kk], b1[n][kk], acc[m + 4][n + 2], 0, 0, 0);
    __builtin_amdgcn_s_setprio(0);
    __builtin_amdgcn_sched_barrier(0);
    __builtin_amdgcn_s_barrier();

    // ---- phase 3: stage t+2 B-ht1 + A-ht1 (rows read in p1/p2); MFMA Q(mh1 x nh0);
    //               tile-boundary counted vmcnt
    if (st){ stB(2, koff, pb); stB(3, koff, pb); stA(2, koff, pb); stA(3, koff, pb); }
    __builtin_amdgcn_sched_barrier(0);
    __builtin_amdgcn_s_barrier();
    __builtin_amdgcn_s_setprio(1);
    #pragma unroll
    for (int kk = 0; kk < 2; kk++)
      #pragma unroll
      for (int m = 0; m < 4; m++)
        #pragma unroll
        for (int n = 0; n < 2; n++)
          acc[m + 4][n] = __builtin_amdgcn_mfma_f32_16x16x32_bf16(a1[m][kk], b0[n][kk], acc[m + 4][n], 0, 0, 0);
    __builtin_amdgcn_s_setprio(0);
    if (t < NT - 1){
      if (st) asm volatile("s_waitcnt vmcnt(8)" ::: "memory");
      else    asm volatile("s_waitcnt vmcnt(0)" ::: "memory");
    }
    __builtin_amdgcn_sched_barrier(0);
    __builtin_amdgcn_s_barrier();
    koff += 64;
  }

  // epilogue
  const int orow0 = br + wr + ((lane >> 4) * 4);
  const int ocol0 = bc + wc_ + (lane & 15);
  #pragma unroll
  for (int m = 0; m < 8; m++){
    #pragma unroll
    for (int n = 0; n < 4; n++){
      #pragma unroll
      for (int rr = 0; rr < 4; rr++){
        int gr = orow0 + m * 16 + rr;
        int gc = ocol0 + n * 16;
        float v = acc[m][n][rr];
        size_t idx = (size_t)gr * ldc + gc;
        if (EPI == EPI_SBIAS)      obf[idx] = f2bf(v + 0.5f * brow[gr]);
        else if (EPI == EPI_GELU)  obf[idx] = f2bf(gelu_exact(v + bcol[gc]));
        else if (EPI == EPI_F32)   ofp[idx] = v;
        else                       ofp[idx] += v;
      }
    }
  }
}

// ---------- m97-structure 128x128 GEMM (kept for the narrow N=1024 G4/G5) ----------
template<int EPI>
__global__ __launch_bounds__(256, 2) void gemm_bt(const u16* __restrict__ A,
    const u16* __restrict__ BT, int M, int N, int K,
    u16* __restrict__ obf, float* __restrict__ ofp,
    const float* __restrict__ bcol, const float* __restrict__ brow){
  __shared__ __align__(16) u16 lsA[128 * 64];
  __shared__ __align__(16) u16 lsB[128 * 64];
  const int t = threadIdx.x;
  const int lane = t & 63;
  const int wave = t >> 6;
  const int br = blockIdx.y * 128;
  const int bc = blockIdx.x * 128;
  const int wr = (wave >> 1) * 64;
  const int wc = (wave & 1) * 64;

  f32x4 acc[4][4] = {};

  size_t aoff[4], boff[4];
  u16 *adst[4], *bdst[4];
  #pragma unroll
  for (int i = 0; i < 4; i++){
    int p = i * 256 + t;
    int row = p >> 3;
    int lc = (p & 7) ^ (row & 7);
    aoff[i] = (size_t)(br + row) * K + lc * 8;
    boff[i] = (size_t)(bc + row) * K + lc * 8;
    adst[i] = lsA + p * 8;
    bdst[i] = lsB + p * 8;
  }

  const int fr = lane & 15;
  const int colb0 = (lane >> 4) * 16;

  for (int kt = 0; kt < K; kt += 64){
    __syncthreads();
    #pragma unroll
    for (int i = 0; i < 4; i++) gload16(A + aoff[i] + kt, adst[i]);
    #pragma unroll
    for (int i = 0; i < 4; i++) gload16(BT + boff[i] + kt, bdst[i]);
    __syncthreads();
    #pragma unroll
    for (int kk = 0; kk < 2; kk++){
      s16x8 af[4], bfr[4];
      #pragma unroll
      for (int m = 0; m < 4; m++){
        int row = wr + m * 16 + fr;
        int off = (row * 128 + kk * 64 + colb0) ^ ((row & 7) << 4);
        af[m] = *(const s16x8*)((const char*)lsA + off);
      }
      #pragma unroll
      for (int n = 0; n < 4; n++){
        int row = wc + n * 16 + fr;
        int off = (row * 128 + kk * 64 + colb0) ^ ((row & 7) << 4);
        bfr[n] = *(const s16x8*)((const char*)lsB + off);
      }
      #pragma unroll
      for (int m = 0; m < 4; m++)
        #pragma unroll
        for (int n = 0; n < 4; n++)
          acc[m][n] = __builtin_amdgcn_mfma_f32_16x16x32_bf16(af[m], bfr[n], acc[m][n], 0, 0, 0);
    }
  }

  const int orow = br + wr + ((lane >> 4) * 4);
  const int ocol = bc + wc + (lane & 15);
  #pragma unroll
  for (int m = 0; m < 4; m++){
    #pragma unroll
    for (int n = 0; n < 4; n++){
      #pragma unroll
      for (int rr = 0; rr < 4; rr++){
        int gr = orow + m * 16 + rr;
        int gc = ocol + n * 16;
        float v = acc[m][n][rr];
        size_t idx = (size_t)gr * N + gc;
        if (EPI == EPI_SBIAS)      obf[idx] = f2bf(v + 0.5f * brow[gr]);
        else if (EPI == EPI_GELU)  obf[idx] = f2bf(gelu_exact(v + bcol[gc]));
        else if (EPI == EPI_F32)   ofp[idx] = v;
        else                       ofp[idx] += v;
      }
    }
  }
}

// ---------- launch ----------
extern "C" void kernel_launch(void* const* d_in, const int* in_sizes, int n_in,
                              void* d_out, int out_size, void* d_ws, size_t ws_size,
                              hipStream_t stream){
  const float* x      = (const float*)d_in[0];
  const float* HpreR  = (const float*)d_in[1];
  const float* HpostR = (const float*)d_in[2];
  const float* HresR  = (const float*)d_in[3];
  const float* W1     = (const float*)d_in[4];
  const float* b1     = (const float*)d_in[5];
  const float* W2     = (const float*)d_in[6];
  const float* b2     = (const float*)d_in[7];
  const float* gpre   = (const float*)d_in[8];
  const float* bpre   = (const float*)d_in[9];
  const float* gpost  = (const float*)d_in[10];
  const float* bpost  = (const float*)d_in[11];
  float* out = (float*)d_out;
  char* w = (char*)d_ws;
  constexpr size_t MBc = 1ull << 20;

  u16*   W1T    = (u16*)(w + 0);          // [8192][4096] 64MB
  u16*   W2T    = (u16*)(w + 64 * MBc);   // [4096][8192] 64MB
  u16*   DPRET  = (u16*)(w + 128 * MBc);  // [4096][1024] 8MB  = (sigmoid(Hpre)-0.5)^T
  u16*   DPOSTT = (u16*)(w + 136 * MBc);  // [1024][4096] 8MB  = (2sigmoid(Hpost)-1)^T
  u16*   HREST  = (u16*)(w + 144 * MBc);  // [1024][1024] 2MB
  u16*   XN     = (u16*)(w + 146 * MBc);  // [8192][1024] 16MB
  u16*   XBF    = (u16*)(w + 162 * MBc);  // [8192][1024] 16MB
  float* S      = (float*)(w + 178 * MBc);// [8192]
  float* A0     = (float*)(w + 179 * MBc);// [1024][1024] fp32 4MB
  float* A0T    = (float*)(w + 183 * MBc);// 4MB
  float* Rv     = (float*)(w + 187 * MBc);// [1024]
  float* Cv     = Rv + 1024;              // [1024]
  u16*   XEXP   = (u16*)(w + 188 * MBc);  // [8192][4096] 64MB (reused chunkwise as h2)
  u16*   H1     = (u16*)(w + 252 * MBc);  // [Mc][8192] bf16 chunk buffer
  float* VAR    = (float*)(w + 252 * MBc);// [8192][1024] fp32 32MB (after H1 dead)

  // chunk size: 4096 rows if workspace allows (peak 316MB), else proven 284MB layout
  const int Mc = (ws_size >= (316ull << 20)) ? 4096 : 2048;
  const int nch = 8192 / Mc;

  dim3 blk(256);

  // weight precompute (transposed to [N][K] for the B^T GEMM)
  transpose_op<OPC_CAST,  u16><<<dim3(128, 64), blk, 0, stream>>>(W1, W1T, 4096, 8192);
  transpose_op<OPC_CAST,  u16><<<dim3(64, 128), blk, 0, stream>>>(W2, W2T, 8192, 4096);
  transpose_op<OPC_SIGM05,u16><<<dim3(64, 16),  blk, 0, stream>>>(HpreR, DPRET, 1024, 4096);
  transpose_op<OPC_SIG2M1,u16><<<dim3(16, 64),  blk, 0, stream>>>(HpostR, DPOSTT, 4096, 1024);

  // sinkhorn (scaling-vector form; exact incl. eps placement)
  sk_softmax_k<<<1024, blk, 0, stream>>>(HresR, A0);
  transpose_op<OPC_CAST, float><<<dim3(16, 16), blk, 0, stream>>>(A0, A0T, 1024, 1024);
  sk_init<<<8, blk, 0, stream>>>(Rv, 2048);
  for (int i = 0; i < 20; i++){
    sk_pass<<<1024, blk, 0, stream>>>(A0,  Cv, Rv);   // row normalize
    sk_pass<<<1024, blk, 0, stream>>>(A0T, Rv, Cv);   // col normalize
  }
  sk_mat<<<1024, blk, 0, stream>>>(A0T, Rv, Cv, HREST);

  // pre-LN (+ fp32 row sums of xn, + bf16 copy of raw x)
  ln1_kernel<<<8192, blk, 0, stream>>>(x, gpre, bpre, XN, XBF, S);

  // G1: x_exp = xn @ (Hpre-0.5) + 0.5*s -> bf16 [8192][4096]   (8-phase 256^2)
  gemm8<EPI_SBIAS><<<dim3(16, 32), dim3(512), 0, stream>>>(XN, DPRET, 1024, 4096,
                                                           XEXP, nullptr, nullptr, S);
  // G2/G3 in Mc-row chunks (h1 chunk buffer; h2 overwrites x_exp chunk)
  for (int c0 = 0; c0 < nch; c0++){
    const u16* ax = XEXP + (size_t)c0 * Mc * 4096;
    u16* h2c      = XEXP + (size_t)c0 * Mc * 4096;
    gemm8<EPI_GELU><<<dim3(32, Mc / 256), dim3(512), 0, stream>>>(ax, W1T, 4096, 8192,
                                                                  H1, nullptr, b1, nullptr);
    gemm8<EPI_GELU><<<dim3(16, Mc / 256), dim3(512), 0, stream>>>(H1, W2T, 8192, 4096,
                                                                  h2c, nullptr, b2, nullptr);
  }
  // G4: var = h2 @ (2sigmoid(Hpost)-1)   (rank-1 rowsum constant cancels in final LN)
  gemm_bt<EPI_F32><<<dim3(8, 64), blk, 0, stream>>>(XEXP, DPOSTT, 8192, 1024, 4096,
                                                    nullptr, VAR, nullptr, nullptr);
  // G5: VAR += x @ Hres
  gemm_bt<EPI_ADDF32><<<dim3(8, 64), blk, 0, stream>>>(XBF, HREST, 8192, 1024, 1024,
                                                       nullptr, VAR, nullptr, nullptr);
  // final LN -> fp32 out
  ln2_kernel<<<8192, blk, 0, stream>>>(VAR, gpost, bpost, out);
}

// Round 4
// 1369.238 us; speedup vs baseline: 1.2079x; 1.1594x over previous
//
#include <hip/hip_runtime.h>

typedef __attribute__((ext_vector_type(4))) float f32x4;
typedef __attribute__((ext_vector_type(8))) short s16x8;
typedef unsigned short u16;
typedef unsigned int u32;

// ---------- helpers ----------
__device__ __forceinline__ u16 f2bf(float f){
  u32 u = __builtin_bit_cast(u32, f);
  u += 0x7fffu + ((u >> 16) & 1u);          // RNE
  return (u16)(u >> 16);
}
__device__ __forceinline__ float gelu_exact(float x){
  return 0.5f * x * (1.0f + erff(x * 0.70710678118654752f));
}
__device__ __forceinline__ float sigmoidf_(float x){
  return 1.0f / (1.0f + expf(-x));
}

// inline-asm LDS read: opaque to the compiler's waitcnt pass (prevents it from
// inserting vmcnt(0) drains for the global_load_lds RAW hazard).
template<int OFF>
__device__ __forceinline__ s16x8 dsr(u32 addr){
  s16x8 r;
  asm volatile("ds_read_b128 %0, %1 offset:%2" : "=v"(r) : "v"(addr), "i"(OFF));
  return r;
}
// guaranteed LDS byte offset (ptrtoint of an addrspace(3) pointer)
__device__ __forceinline__ u32 lds_off(const void* p){
  return (u32)(size_t)(const __attribute__((address_space(3))) char*)p;
}

// 256-thread block reductions (4 waves)
__device__ __forceinline__ float blk_sum(float v, float* red){
  #pragma unroll
  for (int off = 32; off; off >>= 1) v += __shfl_xor(v, off, 64);
  int t = threadIdx.x;
  if ((t & 63) == 0) red[t >> 6] = v;
  __syncthreads();
  float r = red[0] + red[1] + red[2] + red[3];
  __syncthreads();
  return r;
}
__device__ __forceinline__ float blk_max(float v, float* red){
  #pragma unroll
  for (int off = 32; off; off >>= 1) v = fmaxf(v, __shfl_xor(v, off, 64));
  int t = threadIdx.x;
  if ((t & 63) == 0) red[t >> 6] = v;
  __syncthreads();
  float r = fmaxf(fmaxf(red[0], red[1]), fmaxf(red[2], red[3]));
  __syncthreads();
  return r;
}

// ---------- transpose + elementwise op (fp32 in -> bf16/fp32 out, [R][C] -> [C][R]) ----------
enum { OPC_CAST = 0, OPC_SIGM05 = 1, OPC_SIG2M1 = 2 };

template<int OP, typename OutT>
__global__ __launch_bounds__(256) void transpose_op(const float* __restrict__ in,
                                                    OutT* __restrict__ out, int R, int C){
  __shared__ float tile[64][65];
  const int tc = blockIdx.x, tr = blockIdx.y;
  const int c = threadIdx.x & 63, r4 = threadIdx.x >> 6;
  #pragma unroll
  for (int i = 0; i < 16; i++){
    int r = r4 * 16 + i;
    float v = in[(size_t)(tr * 64 + r) * C + tc * 64 + c];
    if (OP == OPC_SIGM05)      v = sigmoidf_(v) - 0.5f;
    else if (OP == OPC_SIG2M1) v = 2.0f * sigmoidf_(v) - 1.0f;
    tile[r][c] = v;
  }
  __syncthreads();
  #pragma unroll
  for (int i = 0; i < 16; i++){
    int r = r4 * 16 + i;
    float v = tile[c][r];
    size_t o = (size_t)(tc * 64 + r) * R + tr * 64 + c;
    if constexpr (sizeof(OutT) == 2) out[o] = f2bf(v);
    else                             out[o] = v;
  }
}

// ---------- sinkhorn ----------
__global__ __launch_bounds__(256) void sk_softmax_k(const float* __restrict__ raw,
                                                    float* __restrict__ A0){
  __shared__ float red[4];
  const int row = blockIdx.x, t = threadIdx.x;
  const float4 v = *(const float4*)(raw + (size_t)row * 1024 + t * 4);
  float mx = fmaxf(fmaxf(v.x, v.y), fmaxf(v.z, v.w));
  mx = blk_max(mx, red);
  float e0 = expf(v.x - mx), e1 = expf(v.y - mx), e2 = expf(v.z - mx), e3 = expf(v.w - mx);
  float s = blk_sum(e0 + e1 + e2 + e3, red);
  float sc = 1024.0f / s;
  float4 o = { e0 * sc, e1 * sc, e2 * sc, e3 * sc };
  *(float4*)(A0 + (size_t)row * 1024 + t * 4) = o;
}

__global__ __launch_bounds__(256) void sk_init(float* p, int n){
  int i = blockIdx.x * 256 + threadIdx.x;
  if (i < n) p[i] = 1.0f;
}

// vupd[row] = vupd[row] / (vupd[row]*dot(Am[row,:], vin) + 1e-8)
__global__ __launch_bounds__(256) void sk_pass(const float* __restrict__ Am,
                                               const float* __restrict__ vin,
                                               float* __restrict__ vupd){
  __shared__ float red[4];
  const int row = blockIdx.x, t = threadIdx.x;
  const float4 a = *(const float4*)(Am + (size_t)row * 1024 + t * 4);
  const float4 b = *(const float4*)(vin + t * 4);
  float d = a.x * b.x + a.y * b.y + a.z * b.z + a.w * b.w;
  d = blk_sum(d, red);
  if (t == 0){ float rv = vupd[row]; vupd[row] = rv / (rv * d + 1e-8f); }
}

// HresT[e][d] = bf16(r[d] * A0T[e][d] * c[e])
__global__ __launch_bounds__(256) void sk_mat(const float* __restrict__ A0T,
                                              const float* __restrict__ r,
                                              const float* __restrict__ c,
                                              u16* __restrict__ HresT){
  const int e = blockIdx.x, t = threadIdx.x;
  const float ce = c[e];
  const float4 a  = *(const float4*)(A0T + (size_t)e * 1024 + t * 4);
  const float4 rv = *(const float4*)(r + t * 4);
  ushort4 o;
  o.x = f2bf(a.x * rv.x * ce); o.y = f2bf(a.y * rv.y * ce);
  o.z = f2bf(a.z * rv.z * ce); o.w = f2bf(a.w * rv.w * ce);
  *(ushort4*)(HresT + (size_t)e * 1024 + t * 4) = o;
}

// ---------- layernorms ----------
__global__ __launch_bounds__(256) void ln1_kernel(const float* __restrict__ x,
    const float* __restrict__ g, const float* __restrict__ b,
    u16* __restrict__ xn, u16* __restrict__ xbf, float* __restrict__ sOut){
  __shared__ float red[4];
  const int row = blockIdx.x, t = threadIdx.x;
  const float4 v = *(const float4*)(x + (size_t)row * 1024 + t * 4);
  float mu = blk_sum(v.x + v.y + v.z + v.w, red) * (1.0f / 1024.0f);
  float d0 = v.x - mu, d1 = v.y - mu, d2 = v.z - mu, d3 = v.w - mu;
  float var = blk_sum(d0 * d0 + d1 * d1 + d2 * d2 + d3 * d3, red) * (1.0f / 1024.0f);
  float rstd = rsqrtf(var + 1e-5f);
  const float4 gv = *(const float4*)(g + t * 4);
  const float4 bv = *(const float4*)(b + t * 4);
  float y0 = d0 * rstd * gv.x + bv.x;
  float y1 = d1 * rstd * gv.y + bv.y;
  float y2 = d2 * rstd * gv.z + bv.z;
  float y3 = d3 * rstd * gv.w + bv.w;
  float ss = blk_sum(y0 + y1 + y2 + y3, red);   // fp32 row-sum of xn (for H_pre 0.5-part)
  if (t == 0) sOut[row] = ss;
  ushort4 o;  o.x = f2bf(y0);  o.y = f2bf(y1);  o.z = f2bf(y2);  o.w = f2bf(y3);
  *(ushort4*)(xn + (size_t)row * 1024 + t * 4) = o;
  ushort4 xo; xo.x = f2bf(v.x); xo.y = f2bf(v.y); xo.z = f2bf(v.z); xo.w = f2bf(v.w);
  *(ushort4*)(xbf + (size_t)row * 1024 + t * 4) = xo;
}

__global__ __launch_bounds__(256) void ln2_kernel(const float* __restrict__ y,
    const float* __restrict__ g, const float* __restrict__ b, float* __restrict__ out){
  __shared__ float red[4];
  const int row = blockIdx.x, t = threadIdx.x;
  const float4 v = *(const float4*)(y + (size_t)row * 1024 + t * 4);
  float mu = blk_sum(v.x + v.y + v.z + v.w, red) * (1.0f / 1024.0f);
  float d0 = v.x - mu, d1 = v.y - mu, d2 = v.z - mu, d3 = v.w - mu;
  float var = blk_sum(d0 * d0 + d1 * d1 + d2 * d2 + d3 * d3, red) * (1.0f / 1024.0f);
  float rstd = rsqrtf(var + 1e-5f);
  const float4 gv = *(const float4*)(g + t * 4);
  const float4 bv = *(const float4*)(b + t * 4);
  float4 o = { d0 * rstd * gv.x + bv.x, d1 * rstd * gv.y + bv.y,
               d2 * rstd * gv.z + bv.z, d3 * rstd * gv.w + bv.w };
  *(float4*)(out + (size_t)row * 1024 + t * 4) = o;
}

enum { EPI_SBIAS = 0, EPI_GELU = 1, EPI_F32 = 2, EPI_ADDF32 = 3 };

__device__ __forceinline__ void gload16(const void* g, void* l){
  __builtin_amdgcn_global_load_lds((const __attribute__((address_space(1))) u32*)g,
                                   (__attribute__((address_space(3))) u32*)l, 16, 0, 0);
}

// ---------- 256x256 8-phase GEMM: C[M,N] = A[M,K](bf16) * BT[N,K](bf16), fp32 accum ----
// 512 threads = 8 waves (2Mx4N). Stage tile t+1 into the opposite dbuf, 2 rounds/phase
// in consumption order. Every counted vmcnt is END-of-phase, BEFORE an s_barrier; the
// published rounds are only ds_read AFTER that barrier (vmcnt is per-wave; the barrier
// is what publishes other waves' staging). Outstanding stays 4..8 in-loop (no drain).
template<int EPI>
__global__ __launch_bounds__(512, 2) void gemm8(const u16* __restrict__ A,
    const u16* __restrict__ BT, int K, int ldc,
    u16* __restrict__ obf, float* __restrict__ ofp,
    const float* __restrict__ bcol, const float* __restrict__ brow){
  __shared__ __align__(16) u16 lsA[2 * 256 * 64];
  __shared__ __align__(16) u16 lsB[2 * 256 * 64];
  const int tid = threadIdx.x;
  const int lane = tid & 63;
  const int wave = tid >> 6;

  // bijective XCD swizzle (all grids here are %8==0)
  const u32 gx = gridDim.x;
  const u32 nwg = gx * gridDim.y;
  const u32 orig = blockIdx.y * gx + blockIdx.x;
  const u32 swzid = (orig & 7) * (nwg >> 3) + (orig >> 3);
  const int br = (int)(swzid / gx) * 256;
  const int bc = (int)(swzid % gx) * 256;

  const int wr  = (wave >> 2) * 128;   // wave row block
  const int wc_ = (wave & 3) * 64;     // wave col block

  // ds_read swizzled bases (true LDS byte offsets)
  const int fr = lane & 15;
  const int colb0 = (lane >> 4) * 16;
  const int swz = colb0 ^ ((fr & 7) << 4);
  const u32 baseA = lds_off(lsA);
  const u32 baseB = lds_off(lsB);
  const u32 sA0 = baseA + (u32)((wr + fr) * 128 + swz);
  const u32 sA1 = baseA + (u32)((wr + fr) * 128 + (swz ^ 64));
  const u32 sB0 = baseB + (u32)((wc_ + fr) * 128 + swz);
  const u32 sB1 = baseB + (u32)((wc_ + fr) * 128 + (swz ^ 64));

  // staging rounds: 512 thr x 16B = 8KB/round; 8 rounds/tile (4 A + 4 B).
  // linear LDS dst + inverse-swizzled global src (rule #21).
  const int r = tid >> 3, s = tid & 7;
  const int lc8 = ((s ^ (r & 7)) * 8);
  const int rb_ = (r & 31) + ((r >> 5) << 6);
  const int rA[4] = { r, r + 128, r + 64, r + 192 };       // rows {0-63,128-191},{64-127,192-255}
  const int rB[4] = { rb_, rb_ + 128, rb_ + 32, rb_ + 160 };
  u32 srcA[4], srcB[4], dstA[4], dstB[4];
  #pragma unroll
  for (int i = 0; i < 4; i++){
    srcA[i] = (u32)(br + rA[i]) * (u32)K + (u32)lc8;
    srcB[i] = (u32)(bc + rB[i]) * (u32)K + (u32)lc8;
    dstA[i] = (u32)(rA[i] * 128 + s * 16);
    dstB[i] = (u32)(rB[i] * 128 + s * 16);
  }
  auto stA = [&](int i, u32 koff, u32 qb){ gload16(A  + srcA[i] + koff, (char*)lsA + qb + dstA[i]); };
  auto stB = [&](int i, u32 koff, u32 qb){ gload16(BT + srcB[i] + koff, (char*)lsB + qb + dstB[i]); };

  const int NT = K >> 6;
  f32x4 acc[8][4] = {};

  // prologue: stage tile0 into buf0 (consumption order), publish rounds A0,A1,B0,B1
  stA(0, 0, 0); stA(1, 0, 0); stB(0, 0, 0); stB(1, 0, 0);
  stB(2, 0, 0); stB(3, 0, 0); stA(2, 0, 0); stA(3, 0, 0);
  asm volatile("s_waitcnt vmcnt(4)" ::: "memory");
  __builtin_amdgcn_sched_barrier(0);
  __builtin_amdgcn_s_barrier();
  __builtin_amdgcn_sched_barrier(0);

  for (int t = 0; t < NT; ++t){
    const u32 pb = (t & 1) ? 32768u : 0u;
    const u32 qb = pb ^ 32768u;
    const bool st = (t + 1) < NT;
    const u32 kn = (u32)(t + 1) << 6;
    const u32 aA0 = sA0 + pb, aA1 = sA1 + pb, bB0 = sB0 + pb, bB1 = sB1 + pb;
    s16x8 a0[4][2], a1[4][2], b0[2][2], b1[2][2];

    // ---- P0: stage A0',A1'; read a0 (rounds A0,A1) + b0 (rounds B0,B1); MFMA Q(mh0,nh0)
    if (st){ stA(0, kn, qb); stA(1, kn, qb); }
    a0[0][0] = dsr<0>(aA0);    a0[0][1] = dsr<0>(aA1);
    a0[1][0] = dsr<2048>(aA0); a0[1][1] = dsr<2048>(aA1);
    a0[2][0] = dsr<4096>(aA0); a0[2][1] = dsr<4096>(aA1);
    a0[3][0] = dsr<6144>(aA0); a0[3][1] = dsr<6144>(aA1);
    b0[0][0] = dsr<0>(bB0);    b0[0][1] = dsr<0>(bB1);
    b0[1][0] = dsr<2048>(bB0); b0[1][1] = dsr<2048>(bB1);
    asm volatile("s_waitcnt lgkmcnt(0)" ::: "memory");
    __builtin_amdgcn_sched_barrier(0);
    __builtin_amdgcn_s_setprio(1);
    #pragma unroll
    for (int kk = 0; kk < 2; kk++)
      #pragma unroll
      for (int m = 0; m < 4; m++)
        #pragma unroll
        for (int n = 0; n < 2; n++)
          acc[m][n] = __builtin_amdgcn_mfma_f32_16x16x32_bf16(a0[m][kk], b0[n][kk], acc[m][n], 0, 0, 0);
    __builtin_amdgcn_s_setprio(0);
    // publish rounds B2,B3 of this tile (oldest 2 outstanding)
    if (st) asm volatile("s_waitcnt vmcnt(4)" ::: "memory");
    else    asm volatile("s_waitcnt vmcnt(2)" ::: "memory");
    __builtin_amdgcn_sched_barrier(0);
    __builtin_amdgcn_s_barrier();
    __builtin_amdgcn_sched_barrier(0);

    // ---- P1: stage B0',B1'; read b1 (rounds B2,B3); MFMA Q(mh0,nh1)
    if (st){ stB(0, kn, qb); stB(1, kn, qb); }
    b1[0][0] = dsr<4096>(bB0); b1[0][1] = dsr<4096>(bB1);
    b1[1][0] = dsr<6144>(bB0); b1[1][1] = dsr<6144>(bB1);
    asm volatile("s_waitcnt lgkmcnt(0)" ::: "memory");
    __builtin_amdgcn_sched_barrier(0);
    __builtin_amdgcn_s_setprio(1);
    #pragma unroll
    for (int kk = 0; kk < 2; kk++)
      #pragma unroll
      for (int m = 0; m < 4; m++)
        #pragma unroll
        for (int n = 0; n < 2; n++)
          acc[m][n + 2] = __builtin_amdgcn_mfma_f32_16x16x32_bf16(a0[m][kk], b1[n][kk], acc[m][n + 2], 0, 0, 0);
    __builtin_amdgcn_s_setprio(0);
    // publish rounds A2,A3 of this tile
    if (st) asm volatile("s_waitcnt vmcnt(4)" ::: "memory");
    else    asm volatile("s_waitcnt vmcnt(0)" ::: "memory");
    __builtin_amdgcn_sched_barrier(0);
    __builtin_amdgcn_s_barrier();
    __builtin_amdgcn_sched_barrier(0);

    // ---- P2: stage B2',B3'; read a1 (rounds A2,A3); MFMA Q(mh1,nh1); no barrier needed
    if (st){ stB(2, kn, qb); stB(3, kn, qb); }
    a1[0][0] = dsr<8192>(aA0);  a1[0][1] = dsr<8192>(aA1);
    a1[1][0] = dsr<10240>(aA0); a1[1][1] = dsr<10240>(aA1);
    a1[2][0] = dsr<12288>(aA0); a1[2][1] = dsr<12288>(aA1);
    a1[3][0] = dsr<14336>(aA0); a1[3][1] = dsr<14336>(aA1);
    asm volatile("s_waitcnt lgkmcnt(0)" ::: "memory");
    __builtin_amdgcn_sched_barrier(0);
    __builtin_amdgcn_s_setprio(1);
    #pragma unroll
    for (int kk = 0; kk < 2; kk++)
      #pragma unroll
      for (int m = 0; m < 4; m++)
        #pragma unroll
        for (int n = 0; n < 2; n++)
          acc[m + 4][n + 2] = __builtin_amdgcn_mfma_f32_16x16x32_bf16(a1[m][kk], b1[n][kk], acc[m + 4][n + 2], 0, 0, 0);
    __builtin_amdgcn_s_setprio(0);
    __builtin_amdgcn_sched_barrier(0);

    // ---- P3: stage A2',A3'; MFMA Q(mh1,nh0) from regs; boundary publish A0',A1',B0',B1'
    if (st){ stA(2, kn, qb); stA(3, kn, qb); }
    __builtin_amdgcn_s_setprio(1);
    #pragma unroll
    for (int kk = 0; kk < 2; kk++)
      #pragma unroll
      for (int m = 0; m < 4; m++)
        #pragma unroll
        for (int n = 0; n < 2; n++)
          acc[m + 4][n] = __builtin_amdgcn_mfma_f32_16x16x32_bf16(a1[m][kk], b0[n][kk], acc[m + 4][n], 0, 0, 0);
    __builtin_amdgcn_s_setprio(0);
    if (st) asm volatile("s_waitcnt vmcnt(4)" ::: "memory");
    __builtin_amdgcn_sched_barrier(0);
    __builtin_amdgcn_s_barrier();
    __builtin_amdgcn_sched_barrier(0);
  }

  // epilogue
  const int orow0 = br + wr + ((lane >> 4) * 4);
  const int ocol0 = bc + wc_ + (lane & 15);
  #pragma unroll
  for (int m = 0; m < 8; m++){
    #pragma unroll
    for (int n = 0; n < 4; n++){
      #pragma unroll
      for (int rr = 0; rr < 4; rr++){
        int gr = orow0 + m * 16 + rr;
        int gc = ocol0 + n * 16;
        float v = acc[m][n][rr];
        size_t idx = (size_t)gr * ldc + gc;
        if (EPI == EPI_SBIAS)      obf[idx] = f2bf(v + 0.5f * brow[gr]);
        else if (EPI == EPI_GELU)  obf[idx] = f2bf(gelu_exact(v + bcol[gc]));
        else if (EPI == EPI_F32)   ofp[idx] = v;
        else                       ofp[idx] += v;
      }
    }
  }
}

// ---------- m97-structure 128x128 GEMM (kept for the narrow N=1024 G4/G5) ----------
template<int EPI>
__global__ __launch_bounds__(256, 2) void gemm_bt(const u16* __restrict__ A,
    const u16* __restrict__ BT, int M, int N, int K,
    u16* __restrict__ obf, float* __restrict__ ofp,
    const float* __restrict__ bcol, const float* __restrict__ brow){
  __shared__ __align__(16) u16 lsA[128 * 64];
  __shared__ __align__(16) u16 lsB[128 * 64];
  const int t = threadIdx.x;
  const int lane = t & 63;
  const int wave = t >> 6;
  const int br = blockIdx.y * 128;
  const int bc = blockIdx.x * 128;
  const int wr = (wave >> 1) * 64;
  const int wc = (wave & 1) * 64;

  f32x4 acc[4][4] = {};

  size_t aoff[4], boff[4];
  u16 *adst[4], *bdst[4];
  #pragma unroll
  for (int i = 0; i < 4; i++){
    int p = i * 256 + t;
    int row = p >> 3;
    int lc = (p & 7) ^ (row & 7);
    aoff[i] = (size_t)(br + row) * K + lc * 8;
    boff[i] = (size_t)(bc + row) * K + lc * 8;
    adst[i] = lsA + p * 8;
    bdst[i] = lsB + p * 8;
  }

  const int fr = lane & 15;
  const int colb0 = (lane >> 4) * 16;

  for (int kt = 0; kt < K; kt += 64){
    __syncthreads();
    #pragma unroll
    for (int i = 0; i < 4; i++) gload16(A + aoff[i] + kt, adst[i]);
    #pragma unroll
    for (int i = 0; i < 4; i++) gload16(BT + boff[i] + kt, bdst[i]);
    __syncthreads();
    #pragma unroll
    for (int kk = 0; kk < 2; kk++){
      s16x8 af[4], bfr[4];
      #pragma unroll
      for (int m = 0; m < 4; m++){
        int row = wr + m * 16 + fr;
        int off = (row * 128 + kk * 64 + colb0) ^ ((row & 7) << 4);
        af[m] = *(const s16x8*)((const char*)lsA + off);
      }
      #pragma unroll
      for (int n = 0; n < 4; n++){
        int row = wc + n * 16 + fr;
        int off = (row * 128 + kk * 64 + colb0) ^ ((row & 7) << 4);
        bfr[n] = *(const s16x8*)((const char*)lsB + off);
      }
      #pragma unroll
      for (int m = 0; m < 4; m++)
        #pragma unroll
        for (int n = 0; n < 4; n++)
          acc[m][n] = __builtin_amdgcn_mfma_f32_16x16x32_bf16(af[m], bfr[n], acc[m][n], 0, 0, 0);
    }
  }

  const int orow = br + wr + ((lane >> 4) * 4);
  const int ocol = bc + wc + (lane & 15);
  #pragma unroll
  for (int m = 0; m < 4; m++){
    #pragma unroll
    for (int n = 0; n < 4; n++){
      #pragma unroll
      for (int rr = 0; rr < 4; rr++){
        int gr = orow + m * 16 + rr;
        int gc = ocol + n * 16;
        float v = acc[m][n][rr];
        size_t idx = (size_t)gr * N + gc;
        if (EPI == EPI_SBIAS)      obf[idx] = f2bf(v + 0.5f * brow[gr]);
        else if (EPI == EPI_GELU)  obf[idx] = f2bf(gelu_exact(v + bcol[gc]));
        else if (EPI == EPI_F32)   ofp[idx] = v;
        else                       ofp[idx] += v;
      }
    }
  }
}

// ---------- launch ----------
extern "C" void kernel_launch(void* const* d_in, const int* in_sizes, int n_in,
                              void* d_out, int out_size, void* d_ws, size_t ws_size,
                              hipStream_t stream){
  const float* x      = (const float*)d_in[0];
  const float* HpreR  = (const float*)d_in[1];
  const float* HpostR = (const float*)d_in[2];
  const float* HresR  = (const float*)d_in[3];
  const float* W1     = (const float*)d_in[4];
  const float* b1     = (const float*)d_in[5];
  const float* W2     = (const float*)d_in[6];
  const float* b2     = (const float*)d_in[7];
  const float* gpre   = (const float*)d_in[8];
  const float* bpre   = (const float*)d_in[9];
  const float* gpost  = (const float*)d_in[10];
  const float* bpost  = (const float*)d_in[11];
  float* out = (float*)d_out;
  char* w = (char*)d_ws;
  constexpr size_t MBc = 1ull << 20;

  u16*   W1T    = (u16*)(w + 0);          // [8192][4096] 64MB
  u16*   W2T    = (u16*)(w + 64 * MBc);   // [4096][8192] 64MB
  u16*   DPRET  = (u16*)(w + 128 * MBc);  // [4096][1024] 8MB  = (sigmoid(Hpre)-0.5)^T
  u16*   DPOSTT = (u16*)(w + 136 * MBc);  // [1024][4096] 8MB  = (2sigmoid(Hpost)-1)^T
  u16*   HREST  = (u16*)(w + 144 * MBc);  // [1024][1024] 2MB
  u16*   XN     = (u16*)(w + 146 * MBc);  // [8192][1024] 16MB
  u16*   XBF    = (u16*)(w + 162 * MBc);  // [8192][1024] 16MB
  float* S      = (float*)(w + 178 * MBc);// [8192]
  float* A0     = (float*)(w + 179 * MBc);// [1024][1024] fp32 4MB
  float* A0T    = (float*)(w + 183 * MBc);// 4MB
  float* Rv     = (float*)(w + 187 * MBc);// [1024]
  float* Cv     = Rv + 1024;              // [1024]
  u16*   XEXP   = (u16*)(w + 188 * MBc);  // [8192][4096] 64MB (reused chunkwise as h2)
  u16*   H1     = (u16*)(w + 252 * MBc);  // [Mc][8192] bf16 chunk buffer
  float* VAR    = (float*)(w + 252 * MBc);// [8192][1024] fp32 32MB (after H1 dead)

  const int Mc = (ws_size >= (316ull << 20)) ? 4096 : 2048;
  const int nch = 8192 / Mc;

  dim3 blk(256);

  // weight precompute (transposed to [N][K] for the B^T GEMM)
  transpose_op<OPC_CAST,  u16><<<dim3(128, 64), blk, 0, stream>>>(W1, W1T, 4096, 8192);
  transpose_op<OPC_CAST,  u16><<<dim3(64, 128), blk, 0, stream>>>(W2, W2T, 8192, 4096);
  transpose_op<OPC_SIGM05,u16><<<dim3(64, 16),  blk, 0, stream>>>(HpreR, DPRET, 1024, 4096);
  transpose_op<OPC_SIG2M1,u16><<<dim3(16, 64),  blk, 0, stream>>>(HpostR, DPOSTT, 4096, 1024);

  // sinkhorn (scaling-vector form; exact incl. eps placement)
  sk_softmax_k<<<1024, blk, 0, stream>>>(HresR, A0);
  transpose_op<OPC_CAST, float><<<dim3(16, 16), blk, 0, stream>>>(A0, A0T, 1024, 1024);
  sk_init<<<8, blk, 0, stream>>>(Rv, 2048);
  for (int i = 0; i < 20; i++){
    sk_pass<<<1024, blk, 0, stream>>>(A0,  Cv, Rv);   // row normalize
    sk_pass<<<1024, blk, 0, stream>>>(A0T, Rv, Cv);   // col normalize
  }
  sk_mat<<<1024, blk, 0, stream>>>(A0T, Rv, Cv, HREST);

  // pre-LN (+ fp32 row sums of xn, + bf16 copy of raw x)
  ln1_kernel<<<8192, blk, 0, stream>>>(x, gpre, bpre, XN, XBF, S);

  // G1: x_exp = xn @ (Hpre-0.5) + 0.5*s -> bf16 [8192][4096]   (8-phase 256^2)
  gemm8<EPI_SBIAS><<<dim3(16, 32), dim3(512), 0, stream>>>(XN, DPRET, 1024, 4096,
                                                           XEXP, nullptr, nullptr, S);
  // G2/G3 in Mc-row chunks (h1 chunk buffer; h2 overwrites x_exp chunk)
  for (int c0 = 0; c0 < nch; c0++){
    const u16* ax = XEXP + (size_t)c0 * Mc * 4096;
    u16* h2c      = XEXP + (size_t)c0 * Mc * 4096;
    gemm8<EPI_GELU><<<dim3(32, Mc / 256), dim3(512), 0, stream>>>(ax, W1T, 4096, 8192,
                                                                  H1, nullptr, b1, nullptr);
    gemm8<EPI_GELU><<<dim3(16, Mc / 256), dim3(512), 0, stream>>>(H1, W2T, 8192, 4096,
                                                                  h2c, nullptr, b2, nullptr);
  }
  // G4: var = h2 @ (2sigmoid(Hpost)-1)   (rank-1 rowsum constant cancels in final LN)
  gemm_bt<EPI_F32><<<dim3(8, 64), blk, 0, stream>>>(XEXP, DPOSTT, 8192, 1024, 4096,
                                                    nullptr, VAR, nullptr, nullptr);
  // G5: VAR += x @ Hres
  gemm_bt<EPI_ADDF32><<<dim3(8, 64), blk, 0, stream>>>(XBF, HREST, 8192, 1024, 1024,
                                                       nullptr, VAR, nullptr, nullptr);
  // final LN -> fp32 out
  ln2_kernel<<<8192, blk, 0, stream>>>(VAR, gpost, bpost, out);
}

// Round 5
// 1331.771 us; speedup vs baseline: 1.2419x; 1.0281x over previous
//
#include <hip/hip_runtime.h>

typedef __attribute__((ext_vector_type(4))) float f32x4;
typedef __attribute__((ext_vector_type(8))) short s16x8;
typedef unsigned short u16;
typedef unsigned int u32;

// ---------- helpers ----------
__device__ __forceinline__ u16 f2bf(float f){
  u32 u = __builtin_bit_cast(u32, f);
  u += 0x7fffu + ((u >> 16) & 1u);          // RNE
  return (u16)(u >> 16);
}
__device__ __forceinline__ float gelu_exact(float x){
  return 0.5f * x * (1.0f + erff(x * 0.70710678118654752f));
}
__device__ __forceinline__ float sigmoidf_(float x){
  return 1.0f / (1.0f + expf(-x));
}

// inline-asm LDS read: opaque to the compiler's waitcnt pass (prevents it from
// inserting vmcnt(0) drains for the global_load_lds RAW hazard).
template<int OFF>
__device__ __forceinline__ s16x8 dsr(u32 addr){
  s16x8 r;
  asm volatile("ds_read_b128 %0, %1 offset:%2" : "=v"(r) : "v"(addr), "i"(OFF));
  return r;
}
// guaranteed LDS byte offset (ptrtoint of an addrspace(3) pointer)
__device__ __forceinline__ u32 lds_off(const void* p){
  return (u32)(size_t)(const __attribute__((address_space(3))) char*)p;
}
template<int N> __device__ __forceinline__ void vmw(){
  asm volatile("s_waitcnt vmcnt(%0)" :: "n"(N) : "memory");
}
template<int N> struct icv { static constexpr int v = N; };
template<bool B> struct bcv { static constexpr bool v = B; };

// 256-thread block reductions (4 waves)
__device__ __forceinline__ float blk_sum(float v, float* red){
  #pragma unroll
  for (int off = 32; off; off >>= 1) v += __shfl_xor(v, off, 64);
  int t = threadIdx.x;
  if ((t & 63) == 0) red[t >> 6] = v;
  __syncthreads();
  float r = red[0] + red[1] + red[2] + red[3];
  __syncthreads();
  return r;
}
__device__ __forceinline__ float blk_max(float v, float* red){
  #pragma unroll
  for (int off = 32; off; off >>= 1) v = fmaxf(v, __shfl_xor(v, off, 64));
  int t = threadIdx.x;
  if ((t & 63) == 0) red[t >> 6] = v;
  __syncthreads();
  float r = fmaxf(fmaxf(red[0], red[1]), fmaxf(red[2], red[3]));
  __syncthreads();
  return r;
}

// ---------- transpose + elementwise op (fp32 in -> bf16/fp32 out, [R][C] -> [C][R]) ----------
enum { OPC_CAST = 0, OPC_SIGM05 = 1, OPC_SIG2M1 = 2 };

template<int OP, typename OutT>
__global__ __launch_bounds__(256) void transpose_op(const float* __restrict__ in,
                                                    OutT* __restrict__ out, int R, int C){
  __shared__ float tile[64][65];
  const int tc = blockIdx.x, tr = blockIdx.y;
  const int c = threadIdx.x & 63, r4 = threadIdx.x >> 6;
  #pragma unroll
  for (int i = 0; i < 16; i++){
    int r = r4 * 16 + i;
    float v = in[(size_t)(tr * 64 + r) * C + tc * 64 + c];
    if (OP == OPC_SIGM05)      v = sigmoidf_(v) - 0.5f;
    else if (OP == OPC_SIG2M1) v = 2.0f * sigmoidf_(v) - 1.0f;
    tile[r][c] = v;
  }
  __syncthreads();
  #pragma unroll
  for (int i = 0; i < 16; i++){
    int r = r4 * 16 + i;
    float v = tile[c][r];
    size_t o = (size_t)(tc * 64 + r) * R + tr * 64 + c;
    if constexpr (sizeof(OutT) == 2) out[o] = f2bf(v);
    else                             out[o] = v;
  }
}

// ---------- sinkhorn ----------
__global__ __launch_bounds__(256) void sk_softmax_k(const float* __restrict__ raw,
                                                    float* __restrict__ A0){
  __shared__ float red[4];
  const int row = blockIdx.x, t = threadIdx.x;
  const float4 v = *(const float4*)(raw + (size_t)row * 1024 + t * 4);
  float mx = fmaxf(fmaxf(v.x, v.y), fmaxf(v.z, v.w));
  mx = blk_max(mx, red);
  float e0 = expf(v.x - mx), e1 = expf(v.y - mx), e2 = expf(v.z - mx), e3 = expf(v.w - mx);
  float s = blk_sum(e0 + e1 + e2 + e3, red);
  float sc = 1024.0f / s;
  float4 o = { e0 * sc, e1 * sc, e2 * sc, e3 * sc };
  *(float4*)(A0 + (size_t)row * 1024 + t * 4) = o;
}

__global__ __launch_bounds__(256) void sk_init(float* p, int n){
  int i = blockIdx.x * 256 + threadIdx.x;
  if (i < n) p[i] = 1.0f;
}

// vupd[row] = vupd[row] / (vupd[row]*dot(Am[row,:], vin) + 1e-8)
__global__ __launch_bounds__(256) void sk_pass(const float* __restrict__ Am,
                                               const float* __restrict__ vin,
                                               float* __restrict__ vupd){
  __shared__ float red[4];
  const int row = blockIdx.x, t = threadIdx.x;
  const float4 a = *(const float4*)(Am + (size_t)row * 1024 + t * 4);
  const float4 b = *(const float4*)(vin + t * 4);
  float d = a.x * b.x + a.y * b.y + a.z * b.z + a.w * b.w;
  d = blk_sum(d, red);
  if (t == 0){ float rv = vupd[row]; vupd[row] = rv / (rv * d + 1e-8f); }
}

// HresT[e][d] = bf16(r[d] * A0T[e][d] * c[e])
__global__ __launch_bounds__(256) void sk_mat(const float* __restrict__ A0T,
                                              const float* __restrict__ r,
                                              const float* __restrict__ c,
                                              u16* __restrict__ HresT){
  const int e = blockIdx.x, t = threadIdx.x;
  const float ce = c[e];
  const float4 a  = *(const float4*)(A0T + (size_t)e * 1024 + t * 4);
  const float4 rv = *(const float4*)(r + t * 4);
  ushort4 o;
  o.x = f2bf(a.x * rv.x * ce); o.y = f2bf(a.y * rv.y * ce);
  o.z = f2bf(a.z * rv.z * ce); o.w = f2bf(a.w * rv.w * ce);
  *(ushort4*)(HresT + (size_t)e * 1024 + t * 4) = o;
}

// ---------- layernorms ----------
__global__ __launch_bounds__(256) void ln1_kernel(const float* __restrict__ x,
    const float* __restrict__ g, const float* __restrict__ b,
    u16* __restrict__ xn, u16* __restrict__ xbf, float* __restrict__ sOut){
  __shared__ float red[4];
  const int row = blockIdx.x, t = threadIdx.x;
  const float4 v = *(const float4*)(x + (size_t)row * 1024 + t * 4);
  float mu = blk_sum(v.x + v.y + v.z + v.w, red) * (1.0f / 1024.0f);
  float d0 = v.x - mu, d1 = v.y - mu, d2 = v.z - mu, d3 = v.w - mu;
  float var = blk_sum(d0 * d0 + d1 * d1 + d2 * d2 + d3 * d3, red) * (1.0f / 1024.0f);
  float rstd = rsqrtf(var + 1e-5f);
  const float4 gv = *(const float4*)(g + t * 4);
  const float4 bv = *(const float4*)(b + t * 4);
  float y0 = d0 * rstd * gv.x + bv.x;
  float y1 = d1 * rstd * gv.y + bv.y;
  float y2 = d2 * rstd * gv.z + bv.z;
  float y3 = d3 * rstd * gv.w + bv.w;
  float ss = blk_sum(y0 + y1 + y2 + y3, red);   // fp32 row-sum of xn (for H_pre 0.5-part)
  if (t == 0) sOut[row] = ss;
  ushort4 o;  o.x = f2bf(y0);  o.y = f2bf(y1);  o.z = f2bf(y2);  o.w = f2bf(y3);
  *(ushort4*)(xn + (size_t)row * 1024 + t * 4) = o;
  ushort4 xo; xo.x = f2bf(v.x); xo.y = f2bf(v.y); xo.z = f2bf(v.z); xo.w = f2bf(v.w);
  *(ushort4*)(xbf + (size_t)row * 1024 + t * 4) = xo;
}

__global__ __launch_bounds__(256) void ln2_kernel(const float* __restrict__ y,
    const float* __restrict__ g, const float* __restrict__ b, float* __restrict__ out){
  __shared__ float red[4];
  const int row = blockIdx.x, t = threadIdx.x;
  const float4 v = *(const float4*)(y + (size_t)row * 1024 + t * 4);
  float mu = blk_sum(v.x + v.y + v.z + v.w, red) * (1.0f / 1024.0f);
  float d0 = v.x - mu, d1 = v.y - mu, d2 = v.z - mu, d3 = v.w - mu;
  float var = blk_sum(d0 * d0 + d1 * d1 + d2 * d2 + d3 * d3, red) * (1.0f / 1024.0f);
  float rstd = rsqrtf(var + 1e-5f);
  const float4 gv = *(const float4*)(g + t * 4);
  const float4 bv = *(const float4*)(b + t * 4);
  float4 o = { d0 * rstd * gv.x + bv.x, d1 * rstd * gv.y + bv.y,
               d2 * rstd * gv.z + bv.z, d3 * rstd * gv.w + bv.w };
  *(float4*)(out + (size_t)row * 1024 + t * 4) = o;
}

enum { EPI_SBIAS = 0, EPI_GELU = 1, EPI_F32 = 2, EPI_ADDF32 = 3 };

__device__ __forceinline__ void gload16(const void* g, void* l){
  __builtin_amdgcn_global_load_lds((const __attribute__((address_space(1))) u32*)g,
                                   (__attribute__((address_space(3))) u32*)l, 16, 0, 0);
}

// ---------- 256x256 8-phase GEMM, deep pipeline (2-tile-ahead staging) ----------
// 512 threads = 8 waves (2Mx4N). LDS regions are dead right after the phase that
// reads them (fragments live in regs), so during tile t we stage tile t+2 into the
// CURRENT buffer's freed regions (and tile t+1's A2/A3 into qb at P0):
//   P0: stage {A2,A3}(t+1)->qb   P1: stage {A0,A1}(t+2)->pb
//   P2: stage {B0,B1}(t+2)->pb   P3: stage {B2,B3}(t+2)->pb
// Issue->consume distance = 6-7 phases (~HBM latency). Steady waits: vmcnt(10) at
// end of P0/P1/P3, each immediately before an s_barrier (publication discipline);
// tails use {10,8,4} then {2,0,-}. Fragment reads are inline-asm ds_read_b128.
template<int EPI>
__global__ __launch_bounds__(512, 2) void gemm8(const u16* __restrict__ A,
    const u16* __restrict__ BT, int K, int ldc,
    u16* __restrict__ obf, float* __restrict__ ofp,
    const float* __restrict__ bcol, const float* __restrict__ brow){
  __shared__ __align__(16) u16 lsA[2 * 256 * 64];
  __shared__ __align__(16) u16 lsB[2 * 256 * 64];
  const int tid = threadIdx.x;
  const int lane = tid & 63;
  const int wave = tid >> 6;

  // bijective XCD swizzle (all grids here are %8==0)
  const u32 gx = gridDim.x;
  const u32 nwg = gx * gridDim.y;
  const u32 orig = blockIdx.y * gx + blockIdx.x;
  const u32 swzid = (orig & 7) * (nwg >> 3) + (orig >> 3);
  const int br = (int)(swzid / gx) * 256;
  const int bc = (int)(swzid % gx) * 256;

  const int wr  = (wave >> 2) * 128;   // wave row block
  const int wc_ = (wave & 3) * 64;     // wave col block

  // ds_read swizzled bases (true LDS byte offsets)
  const int fr = lane & 15;
  const int colb0 = (lane >> 4) * 16;
  const int swz = colb0 ^ ((fr & 7) << 4);
  const u32 baseA = lds_off(lsA);
  const u32 baseB = lds_off(lsB);
  const u32 sA0 = baseA + (u32)((wr + fr) * 128 + swz);
  const u32 sA1 = baseA + (u32)((wr + fr) * 128 + (swz ^ 64));
  const u32 sB0 = baseB + (u32)((wc_ + fr) * 128 + swz);
  const u32 sB1 = baseB + (u32)((wc_ + fr) * 128 + (swz ^ 64));

  // staging rounds: 512 thr x 16B = 8KB/round; 8 rounds/tile (4 A + 4 B).
  // linear LDS dst + inverse-swizzled global src (rule #21).
  const int r = tid >> 3, s = tid & 7;
  const int lc8 = ((s ^ (r & 7)) * 8);
  const int rb_ = (r & 31) + ((r >> 5) << 6);
  const int rA[4] = { r, r + 128, r + 64, r + 192 };       // A0:0-63 A1:128-191 A2:64-127 A3:192-255
  const int rB[4] = { rb_, rb_ + 128, rb_ + 32, rb_ + 160 };
  u32 srcA[4], srcB[4], dstA[4], dstB[4];
  #pragma unroll
  for (int i = 0; i < 4; i++){
    srcA[i] = (u32)(br + rA[i]) * (u32)K + (u32)lc8;
    srcB[i] = (u32)(bc + rB[i]) * (u32)K + (u32)lc8;
    dstA[i] = (u32)(rA[i] * 128 + s * 16);
    dstB[i] = (u32)(rB[i] * 128 + s * 16);
  }
  auto stA = [&](int i, u32 koff, u32 qb){ gload16(A  + srcA[i] + koff, (char*)lsA + qb + dstA[i]); };
  auto stB = [&](int i, u32 koff, u32 qb){ gload16(BT + srcB[i] + koff, (char*)lsB + qb + dstB[i]); };

  const int NT = K >> 6;
  f32x4 acc[8][4] = {};

  auto tile_body = [&](int t, auto W0_, auto W1_, auto W3_, auto ST0_, auto STR_){
    constexpr int  W0  = decltype(W0_)::v;
    constexpr int  W1  = decltype(W1_)::v;
    constexpr int  W3  = decltype(W3_)::v;
    constexpr bool ST0 = decltype(ST0_)::v;
    constexpr bool STR = decltype(STR_)::v;
    const u32 pb = (t & 1) ? 32768u : 0u;
    const u32 qb = pb ^ 32768u;
    const u32 k1 = (u32)(t + 1) << 6;
    const u32 k2 = (u32)(t + 2) << 6;
    const u32 aA0 = sA0 + pb, aA1 = sA1 + pb, bB0 = sB0 + pb, bB1 = sB1 + pb;
    s16x8 a0[4][2], a1[4][2], b0[2][2], b1[2][2];

    // ---- P0: stage {A2,A3}(t+1)->qb; read a0 (A0,A1) + b0 (B0,B1); MFMA Q(mh0,nh0)
    if constexpr (ST0){ stA(2, k1, qb); stA(3, k1, qb); }
    a0[0][0] = dsr<0>(aA0);    a0[0][1] = dsr<0>(aA1);
    a0[1][0] = dsr<2048>(aA0); a0[1][1] = dsr<2048>(aA1);
    a0[2][0] = dsr<4096>(aA0); a0[2][1] = dsr<4096>(aA1);
    a0[3][0] = dsr<6144>(aA0); a0[3][1] = dsr<6144>(aA1);
    b0[0][0] = dsr<0>(bB0);    b0[0][1] = dsr<0>(bB1);
    b0[1][0] = dsr<2048>(bB0); b0[1][1] = dsr<2048>(bB1);
    asm volatile("s_waitcnt lgkmcnt(0)" ::: "memory");
    __builtin_amdgcn_sched_barrier(0);
    __builtin_amdgcn_s_setprio(1);
    #pragma unroll
    for (int kk = 0; kk < 2; kk++)
      #pragma unroll
      for (int m = 0; m < 4; m++)
        #pragma unroll
        for (int n = 0; n < 2; n++)
          acc[m][n] = __builtin_amdgcn_mfma_f32_16x16x32_bf16(a0[m][kk], b0[n][kk], acc[m][n], 0, 0, 0);
    __builtin_amdgcn_s_setprio(0);
    vmw<W0>();
    __builtin_amdgcn_sched_barrier(0);
    __builtin_amdgcn_s_barrier();
    __builtin_amdgcn_sched_barrier(0);

    // ---- P1: stage {A0,A1}(t+2)->pb; read b1 (B2,B3); MFMA Q(mh0,nh1)
    if constexpr (STR){ stA(0, k2, pb); stA(1, k2, pb); }
    b1[0][0] = dsr<4096>(bB0); b1[0][1] = dsr<4096>(bB1);
    b1[1][0] = dsr<6144>(bB0); b1[1][1] = dsr<6144>(bB1);
    asm volatile("s_waitcnt lgkmcnt(0)" ::: "memory");
    __builtin_amdgcn_sched_barrier(0);
    __builtin_amdgcn_s_setprio(1);
    #pragma unroll
    for (int kk = 0; kk < 2; kk++)
      #pragma unroll
      for (int m = 0; m < 4; m++)
        #pragma unroll
        for (int n = 0; n < 2; n++)
          acc[m][n + 2] = __builtin_amdgcn_mfma_f32_16x16x32_bf16(a0[m][kk], b1[n][kk], acc[m][n + 2], 0, 0, 0);
    __builtin_amdgcn_s_setprio(0);
    vmw<W1>();
    __builtin_amdgcn_sched_barrier(0);
    __builtin_amdgcn_s_barrier();
    __builtin_amdgcn_sched_barrier(0);

    // ---- P2: stage {B0,B1}(t+2)->pb; read a1 (A2,A3); MFMA Q(mh1,nh1); no barrier
    if constexpr (STR){ stB(0, k2, pb); stB(1, k2, pb); }
    a1[0][0] = dsr<8192>(aA0);  a1[0][1] = dsr<8192>(aA1);
    a1[1][0] = dsr<10240>(aA0); a1[1][1] = dsr<10240>(aA1);
    a1[2][0] = dsr<12288>(aA0); a1[2][1] = dsr<12288>(aA1);
    a1[3][0] = dsr<14336>(aA0); a1[3][1] = dsr<14336>(aA1);
    asm volatile("s_waitcnt lgkmcnt(0)" ::: "memory");
    __builtin_amdgcn_sched_barrier(0);
    __builtin_amdgcn_s_setprio(1);
    #pragma unroll
    for (int kk = 0; kk < 2; kk++)
      #pragma unroll
      for (int m = 0; m < 4; m++)
        #pragma unroll
        for (int n = 0; n < 2; n++)
          acc[m + 4][n + 2] = __builtin_amdgcn_mfma_f32_16x16x32_bf16(a1[m][kk], b1[n][kk], acc[m + 4][n + 2], 0, 0, 0);
    __builtin_amdgcn_s_setprio(0);
    __builtin_amdgcn_sched_barrier(0);

    // ---- P3: stage {B2,B3}(t+2)->pb; MFMA Q(mh1,nh0) from regs; boundary wait
    if constexpr (STR){ stB(2, k2, pb); stB(3, k2, pb); }
    __builtin_amdgcn_s_setprio(1);
    #pragma unroll
    for (int kk = 0; kk < 2; kk++)
      #pragma unroll
      for (int m = 0; m < 4; m++)
        #pragma unroll
        for (int n = 0; n < 2; n++)
          acc[m + 4][n] = __builtin_amdgcn_mfma_f32_16x16x32_bf16(a1[m][kk], b0[n][kk], acc[m + 4][n], 0, 0, 0);
    __builtin_amdgcn_s_setprio(0);
    if constexpr (W3 >= 0){
      vmw<W3>();
      __builtin_amdgcn_sched_barrier(0);
      __builtin_amdgcn_s_barrier();
      __builtin_amdgcn_sched_barrier(0);
    }
  };

  // prologue: tile0 all 8 rounds + tile1 first 6 rounds, consumption order.
  stA(0, 0, 0); stA(1, 0, 0); stB(0, 0, 0); stB(1, 0, 0);
  stB(2, 0, 0); stB(3, 0, 0); stA(2, 0, 0); stA(3, 0, 0);
  stA(0, 64, 32768u); stA(1, 64, 32768u); stB(0, 64, 32768u); stB(1, 64, 32768u);
  stB(2, 64, 32768u); stB(3, 64, 32768u);
  vmw<10>();
  __builtin_amdgcn_sched_barrier(0);
  __builtin_amdgcn_s_barrier();
  __builtin_amdgcn_sched_barrier(0);

  for (int t = 0; t < NT - 2; ++t)
    tile_body(t, icv<10>{}, icv<10>{}, icv<10>{}, bcv<true>{}, bcv<true>{});
  tile_body(NT - 2, icv<10>{}, icv<8>{}, icv<4>{}, bcv<true>{}, bcv<false>{});
  tile_body(NT - 1, icv<2>{},  icv<0>{}, icv<-1>{}, bcv<false>{}, bcv<false>{});

  // epilogue
  const int orow0 = br + wr + ((lane >> 4) * 4);
  const int ocol0 = bc + wc_ + (lane & 15);
  #pragma unroll
  for (int m = 0; m < 8; m++){
    #pragma unroll
    for (int n = 0; n < 4; n++){
      #pragma unroll
      for (int rr = 0; rr < 4; rr++){
        int gr = orow0 + m * 16 + rr;
        int gc = ocol0 + n * 16;
        float v = acc[m][n][rr];
        size_t idx = (size_t)gr * ldc + gc;
        if (EPI == EPI_SBIAS)      obf[idx] = f2bf(v + 0.5f * brow[gr]);
        else if (EPI == EPI_GELU)  obf[idx] = f2bf(gelu_exact(v + bcol[gc]));
        else if (EPI == EPI_F32)   ofp[idx] = v;
        else                       ofp[idx] += v;
      }
    }
  }
}

// ---------- m97-structure 128x128 GEMM (kept for the narrow N=1024 G4/G5) ----------
template<int EPI>
__global__ __launch_bounds__(256, 2) void gemm_bt(const u16* __restrict__ A,
    const u16* __restrict__ BT, int M, int N, int K,
    u16* __restrict__ obf, float* __restrict__ ofp,
    const float* __restrict__ bcol, const float* __restrict__ brow){
  __shared__ __align__(16) u16 lsA[128 * 64];
  __shared__ __align__(16) u16 lsB[128 * 64];
  const int t = threadIdx.x;
  const int lane = t & 63;
  const int wave = t >> 6;
  const int br = blockIdx.y * 128;
  const int bc = blockIdx.x * 128;
  const int wr = (wave >> 1) * 64;
  const int wc = (wave & 1) * 64;

  f32x4 acc[4][4] = {};

  size_t aoff[4], boff[4];
  u16 *adst[4], *bdst[4];
  #pragma unroll
  for (int i = 0; i < 4; i++){
    int p = i * 256 + t;
    int row = p >> 3;
    int lc = (p & 7) ^ (row & 7);
    aoff[i] = (size_t)(br + row) * K + lc * 8;
    boff[i] = (size_t)(bc + row) * K + lc * 8;
    adst[i] = lsA + p * 8;
    bdst[i] = lsB + p * 8;
  }

  const int fr = lane & 15;
  const int colb0 = (lane >> 4) * 16;

  for (int kt = 0; kt < K; kt += 64){
    __syncthreads();
    #pragma unroll
    for (int i = 0; i < 4; i++) gload16(A + aoff[i] + kt, adst[i]);
    #pragma unroll
    for (int i = 0; i < 4; i++) gload16(BT + boff[i] + kt, bdst[i]);
    __syncthreads();
    #pragma unroll
    for (int kk = 0; kk < 2; kk++){
      s16x8 af[4], bfr[4];
      #pragma unroll
      for (int m = 0; m < 4; m++){
        int row = wr + m * 16 + fr;
        int off = (row * 128 + kk * 64 + colb0) ^ ((row & 7) << 4);
        af[m] = *(const s16x8*)((const char*)lsA + off);
      }
      #pragma unroll
      for (int n = 0; n < 4; n++){
        int row = wc + n * 16 + fr;
        int off = (row * 128 + kk * 64 + colb0) ^ ((row & 7) << 4);
        bfr[n] = *(const s16x8*)((const char*)lsB + off);
      }
      #pragma unroll
      for (int m = 0; m < 4; m++)
        #pragma unroll
        for (int n = 0; n < 4; n++)
          acc[m][n] = __builtin_amdgcn_mfma_f32_16x16x32_bf16(af[m], bfr[n], acc[m][n], 0, 0, 0);
    }
  }

  const int orow = br + wr + ((lane >> 4) * 4);
  const int ocol = bc + wc + (lane & 15);
  #pragma unroll
  for (int m = 0; m < 4; m++){
    #pragma unroll
    for (int n = 0; n < 4; n++){
      #pragma unroll
      for (int rr = 0; rr < 4; rr++){
        int gr = orow + m * 16 + rr;
        int gc = ocol + n * 16;
        float v = acc[m][n][rr];
        size_t idx = (size_t)gr * N + gc;
        if (EPI == EPI_SBIAS)      obf[idx] = f2bf(v + 0.5f * brow[gr]);
        else if (EPI == EPI_GELU)  obf[idx] = f2bf(gelu_exact(v + bcol[gc]));
        else if (EPI == EPI_F32)   ofp[idx] = v;
        else                       ofp[idx] += v;
      }
    }
  }
}

// ---------- launch ----------
extern "C" void kernel_launch(void* const* d_in, const int* in_sizes, int n_in,
                              void* d_out, int out_size, void* d_ws, size_t ws_size,
                              hipStream_t stream){
  const float* x      = (const float*)d_in[0];
  const float* HpreR  = (const float*)d_in[1];
  const float* HpostR = (const float*)d_in[2];
  const float* HresR  = (const float*)d_in[3];
  const float* W1     = (const float*)d_in[4];
  const float* b1     = (const float*)d_in[5];
  const float* W2     = (const float*)d_in[6];
  const float* b2     = (const float*)d_in[7];
  const float* gpre   = (const float*)d_in[8];
  const float* bpre   = (const float*)d_in[9];
  const float* gpost  = (const float*)d_in[10];
  const float* bpost  = (const float*)d_in[11];
  float* out = (float*)d_out;
  char* w = (char*)d_ws;
  constexpr size_t MBc = 1ull << 20;

  u16*   W1T    = (u16*)(w + 0);          // [8192][4096] 64MB
  u16*   W2T    = (u16*)(w + 64 * MBc);   // [4096][8192] 64MB
  u16*   DPRET  = (u16*)(w + 128 * MBc);  // [4096][1024] 8MB  = (sigmoid(Hpre)-0.5)^T
  u16*   DPOSTT = (u16*)(w + 136 * MBc);  // [1024][4096] 8MB  = (2sigmoid(Hpost)-1)^T
  u16*   HREST  = (u16*)(w + 144 * MBc);  // [1024][1024] 2MB
  u16*   XN     = (u16*)(w + 146 * MBc);  // [8192][1024] 16MB
  u16*   XBF    = (u16*)(w + 162 * MBc);  // [8192][1024] 16MB
  float* S      = (float*)(w + 178 * MBc);// [8192]
  float* A0     = (float*)(w + 179 * MBc);// [1024][1024] fp32 4MB
  float* A0T    = (float*)(w + 183 * MBc);// 4MB
  float* Rv     = (float*)(w + 187 * MBc);// [1024]
  float* Cv     = Rv + 1024;              // [1024]
  u16*   XEXP   = (u16*)(w + 188 * MBc);  // [8192][4096] 64MB (reused chunkwise as h2)
  u16*   H1     = (u16*)(w + 252 * MBc);  // [Mc][8192] bf16 chunk buffer
  float* VAR    = (float*)(w + 252 * MBc);// [8192][1024] fp32 32MB (after H1 dead)

  const int Mc = (ws_size >= (316ull << 20)) ? 4096 : 2048;
  const int nch = 8192 / Mc;

  dim3 blk(256);

  // weight precompute (transposed to [N][K] for the B^T GEMM)
  transpose_op<OPC_CAST,  u16><<<dim3(128, 64), blk, 0, stream>>>(W1, W1T, 4096, 8192);
  transpose_op<OPC_CAST,  u16><<<dim3(64, 128), blk, 0, stream>>>(W2, W2T, 8192, 4096);
  transpose_op<OPC_SIGM05,u16><<<dim3(64, 16),  blk, 0, stream>>>(HpreR, DPRET, 1024, 4096);
  transpose_op<OPC_SIG2M1,u16><<<dim3(16, 64),  blk, 0, stream>>>(HpostR, DPOSTT, 4096, 1024);

  // sinkhorn (scaling-vector form; exact incl. eps placement)
  sk_softmax_k<<<1024, blk, 0, stream>>>(HresR, A0);
  transpose_op<OPC_CAST, float><<<dim3(16, 16), blk, 0, stream>>>(A0, A0T, 1024, 1024);
  sk_init<<<8, blk, 0, stream>>>(Rv, 2048);
  for (int i = 0; i < 20; i++){
    sk_pass<<<1024, blk, 0, stream>>>(A0,  Cv, Rv);   // row normalize
    sk_pass<<<1024, blk, 0, stream>>>(A0T, Rv, Cv);   // col normalize
  }
  sk_mat<<<1024, blk, 0, stream>>>(A0T, Rv, Cv, HREST);

  // pre-LN (+ fp32 row sums of xn, + bf16 copy of raw x)
  ln1_kernel<<<8192, blk, 0, stream>>>(x, gpre, bpre, XN, XBF, S);

  // G1: x_exp = xn @ (Hpre-0.5) + 0.5*s -> bf16 [8192][4096]   (8-phase 256^2)
  gemm8<EPI_SBIAS><<<dim3(16, 32), dim3(512), 0, stream>>>(XN, DPRET, 1024, 4096,
                                                           XEXP, nullptr, nullptr, S);
  // G2/G3 in Mc-row chunks (h1 chunk buffer; h2 overwrites x_exp chunk)
  for (int c0 = 0; c0 < nch; c0++){
    const u16* ax = XEXP + (size_t)c0 * Mc * 4096;
    u16* h2c      = XEXP + (size_t)c0 * Mc * 4096;
    gemm8<EPI_GELU><<<dim3(32, Mc / 256), dim3(512), 0, stream>>>(ax, W1T, 4096, 8192,
                                                                  H1, nullptr, b1, nullptr);
    gemm8<EPI_GELU><<<dim3(16, Mc / 256), dim3(512), 0, stream>>>(H1, W2T, 8192, 4096,
                                                                  h2c, nullptr, b2, nullptr);
  }
  // G4: var = h2 @ (2sigmoid(Hpost)-1)   (rank-1 rowsum constant cancels in final LN)
  gemm_bt<EPI_F32><<<dim3(8, 64), blk, 0, stream>>>(XEXP, DPOSTT, 8192, 1024, 4096,
                                                    nullptr, VAR, nullptr, nullptr);
  // G5: VAR += x @ Hres
  gemm_bt<EPI_ADDF32><<<dim3(8, 64), blk, 0, stream>>>(XBF, HREST, 8192, 1024, 1024,
                                                       nullptr, VAR, nullptr, nullptr);
  // final LN -> fp32 out
  ln2_kernel<<<8192, blk, 0, stream>>>(VAR, gpost, bpost, out);
}

// Round 6
// 1325.041 us; speedup vs baseline: 1.2482x; 1.0051x over previous
//
#include <hip/hip_runtime.h>

typedef __attribute__((ext_vector_type(4))) float f32x4;
typedef __attribute__((ext_vector_type(8))) short s16x8;
typedef unsigned short u16;
typedef unsigned int u32;

// ---------- helpers ----------
__device__ __forceinline__ u16 f2bf(float f){
  u32 u = __builtin_bit_cast(u32, f);
  u += 0x7fffu + ((u >> 16) & 1u);          // RNE
  return (u16)(u >> 16);
}
__device__ __forceinline__ float gelu_exact(float x){
  return 0.5f * x * (1.0f + erff(x * 0.70710678118654752f));
}
__device__ __forceinline__ float sigmoidf_(float x){
  return 1.0f / (1.0f + expf(-x));
}

// inline-asm LDS read: opaque to the compiler's waitcnt pass (prevents it from
// inserting vmcnt(0) drains for the global_load_lds RAW hazard).
template<int OFF>
__device__ __forceinline__ s16x8 dsr(u32 addr){
  s16x8 r;
  asm volatile("ds_read_b128 %0, %1 offset:%2" : "=v"(r) : "v"(addr), "i"(OFF));
  return r;
}
// guaranteed LDS byte offset (ptrtoint of an addrspace(3) pointer)
__device__ __forceinline__ u32 lds_off(const void* p){
  return (u32)(size_t)(const __attribute__((address_space(3))) char*)p;
}
template<int N> __device__ __forceinline__ void vmw(){
  asm volatile("s_waitcnt vmcnt(%0)" :: "n"(N) : "memory");
}
template<int N> __device__ __forceinline__ void lgw(){
  asm volatile("s_waitcnt lgkmcnt(%0)" :: "n"(N) : "memory");
}
template<int N> struct icv { static constexpr int v = N; };
template<bool B> struct bcv { static constexpr bool v = B; };

// 256-thread block reductions (4 waves)
__device__ __forceinline__ float blk_sum(float v, float* red){
  #pragma unroll
  for (int off = 32; off; off >>= 1) v += __shfl_xor(v, off, 64);
  int t = threadIdx.x;
  if ((t & 63) == 0) red[t >> 6] = v;
  __syncthreads();
  float r = red[0] + red[1] + red[2] + red[3];
  __syncthreads();
  return r;
}
__device__ __forceinline__ float blk_max(float v, float* red){
  #pragma unroll
  for (int off = 32; off; off >>= 1) v = fmaxf(v, __shfl_xor(v, off, 64));
  int t = threadIdx.x;
  if ((t & 63) == 0) red[t >> 6] = v;
  __syncthreads();
  float r = fmaxf(fmaxf(red[0], red[1]), fmaxf(red[2], red[3]));
  __syncthreads();
  return r;
}

// ---------- transpose + elementwise op (fp32 in -> bf16/fp32 out, [R][C] -> [C][R]) ----------
enum { OPC_CAST = 0, OPC_SIGM05 = 1, OPC_SIG2M1 = 2 };

template<int OP, typename OutT>
__global__ __launch_bounds__(256) void transpose_op(const float* __restrict__ in,
                                                    OutT* __restrict__ out, int R, int C){
  __shared__ float tile[64][65];
  const int tc = blockIdx.x, tr = blockIdx.y;
  const int c = threadIdx.x & 63, r4 = threadIdx.x >> 6;
  #pragma unroll
  for (int i = 0; i < 16; i++){
    int r = r4 * 16 + i;
    float v = in[(size_t)(tr * 64 + r) * C + tc * 64 + c];
    if (OP == OPC_SIGM05)      v = sigmoidf_(v) - 0.5f;
    else if (OP == OPC_SIG2M1) v = 2.0f * sigmoidf_(v) - 1.0f;
    tile[r][c] = v;
  }
  __syncthreads();
  #pragma unroll
  for (int i = 0; i < 16; i++){
    int r = r4 * 16 + i;
    float v = tile[c][r];
    size_t o = (size_t)(tc * 64 + r) * R + tr * 64 + c;
    if constexpr (sizeof(OutT) == 2) out[o] = f2bf(v);
    else                             out[o] = v;
  }
}

// ---------- sinkhorn ----------
__global__ __launch_bounds__(256) void sk_softmax_k(const float* __restrict__ raw,
                                                    float* __restrict__ A0){
  __shared__ float red[4];
  const int row = blockIdx.x, t = threadIdx.x;
  const float4 v = *(const float4*)(raw + (size_t)row * 1024 + t * 4);
  float mx = fmaxf(fmaxf(v.x, v.y), fmaxf(v.z, v.w));
  mx = blk_max(mx, red);
  float e0 = expf(v.x - mx), e1 = expf(v.y - mx), e2 = expf(v.z - mx), e3 = expf(v.w - mx);
  float s = blk_sum(e0 + e1 + e2 + e3, red);
  float sc = 1024.0f / s;
  float4 o = { e0 * sc, e1 * sc, e2 * sc, e3 * sc };
  *(float4*)(A0 + (size_t)row * 1024 + t * 4) = o;
}

__global__ __launch_bounds__(256) void sk_init(float* p, int n){
  int i = blockIdx.x * 256 + threadIdx.x;
  if (i < n) p[i] = 1.0f;
}

// vupd[row] = vupd[row] / (vupd[row]*dot(Am[row,:], vin) + 1e-8)
__global__ __launch_bounds__(256) void sk_pass(const float* __restrict__ Am,
                                               const float* __restrict__ vin,
                                               float* __restrict__ vupd){
  __shared__ float red[4];
  const int row = blockIdx.x, t = threadIdx.x;
  const float4 a = *(const float4*)(Am + (size_t)row * 1024 + t * 4);
  const float4 b = *(const float4*)(vin + t * 4);
  float d = a.x * b.x + a.y * b.y + a.z * b.z + a.w * b.w;
  d = blk_sum(d, red);
  if (t == 0){ float rv = vupd[row]; vupd[row] = rv / (rv * d + 1e-8f); }
}

// HresT[e][d] = bf16(r[d] * A0T[e][d] * c[e])
__global__ __launch_bounds__(256) void sk_mat(const float* __restrict__ A0T,
                                              const float* __restrict__ r,
                                              const float* __restrict__ c,
                                              u16* __restrict__ HresT){
  const int e = blockIdx.x, t = threadIdx.x;
  const float ce = c[e];
  const float4 a  = *(const float4*)(A0T + (size_t)e * 1024 + t * 4);
  const float4 rv = *(const float4*)(r + t * 4);
  ushort4 o;
  o.x = f2bf(a.x * rv.x * ce); o.y = f2bf(a.y * rv.y * ce);
  o.z = f2bf(a.z * rv.z * ce); o.w = f2bf(a.w * rv.w * ce);
  *(ushort4*)(HresT + (size_t)e * 1024 + t * 4) = o;
}

// ---------- layernorms ----------
__global__ __launch_bounds__(256) void ln1_kernel(const float* __restrict__ x,
    const float* __restrict__ g, const float* __restrict__ b,
    u16* __restrict__ xn, u16* __restrict__ xbf, float* __restrict__ sOut){
  __shared__ float red[4];
  const int row = blockIdx.x, t = threadIdx.x;
  const float4 v = *(const float4*)(x + (size_t)row * 1024 + t * 4);
  float mu = blk_sum(v.x + v.y + v.z + v.w, red) * (1.0f / 1024.0f);
  float d0 = v.x - mu, d1 = v.y - mu, d2 = v.z - mu, d3 = v.w - mu;
  float var = blk_sum(d0 * d0 + d1 * d1 + d2 * d2 + d3 * d3, red) * (1.0f / 1024.0f);
  float rstd = rsqrtf(var + 1e-5f);
  const float4 gv = *(const float4*)(g + t * 4);
  const float4 bv = *(const float4*)(b + t * 4);
  float y0 = d0 * rstd * gv.x + bv.x;
  float y1 = d1 * rstd * gv.y + bv.y;
  float y2 = d2 * rstd * gv.z + bv.z;
  float y3 = d3 * rstd * gv.w + bv.w;
  float ss = blk_sum(y0 + y1 + y2 + y3, red);   // fp32 row-sum of xn (for H_pre 0.5-part)
  if (t == 0) sOut[row] = ss;
  ushort4 o;  o.x = f2bf(y0);  o.y = f2bf(y1);  o.z = f2bf(y2);  o.w = f2bf(y3);
  *(ushort4*)(xn + (size_t)row * 1024 + t * 4) = o;
  ushort4 xo; xo.x = f2bf(v.x); xo.y = f2bf(v.y); xo.z = f2bf(v.z); xo.w = f2bf(v.w);
  *(ushort4*)(xbf + (size_t)row * 1024 + t * 4) = xo;
}

__global__ __launch_bounds__(256) void ln2_kernel(const float* __restrict__ y,
    const float* __restrict__ g, const float* __restrict__ b, float* __restrict__ out){
  __shared__ float red[4];
  const int row = blockIdx.x, t = threadIdx.x;
  const float4 v = *(const float4*)(y + (size_t)row * 1024 + t * 4);
  float mu = blk_sum(v.x + v.y + v.z + v.w, red) * (1.0f / 1024.0f);
  float d0 = v.x - mu, d1 = v.y - mu, d2 = v.z - mu, d3 = v.w - mu;
  float var = blk_sum(d0 * d0 + d1 * d1 + d2 * d2 + d3 * d3, red) * (1.0f / 1024.0f);
  float rstd = rsqrtf(var + 1e-5f);
  const float4 gv = *(const float4*)(g + t * 4);
  const float4 bv = *(const float4*)(b + t * 4);
  float4 o = { d0 * rstd * gv.x + bv.x, d1 * rstd * gv.y + bv.y,
               d2 * rstd * gv.z + bv.z, d3 * rstd * gv.w + bv.w };
  *(float4*)(out + (size_t)row * 1024 + t * 4) = o;
}

enum { EPI_SBIAS = 0, EPI_GELU = 1, EPI_F32 = 2, EPI_ADDF32 = 3 };

__device__ __forceinline__ void gload16(const void* g, void* l){
  __builtin_amdgcn_global_load_lds((const __attribute__((address_space(1))) u32*)g,
                                   (__attribute__((address_space(3))) u32*)l, 16, 0, 0);
}

// ---------- 256x256 GEMM, deep pipeline + within-tile ds_read read-ahead ----------
// 512 threads = 8 waves (2Mx4N). Staging (per tile t): P0 {A2,A3}(t+1)->qb,
// P1 {A0,A1}(t+2)->pb, P2 {B0,B1}(t+2)->pb, P3 {B2,B3}(t+2)->pb (regions freed by
// prior phases; publication via end-of-phase vmcnt+s_barrier pairs; retire is
// in-order so vmcnt(8) = "everything but the newest 4 rounds").
// ds_reads are issued a phase ahead of consumption: P0 issues a0+b0+b1 (16),
// waits lgkmcnt(4) (b1 in flight under Q00); P1 issues a1(8), waits lgkmcnt(8);
// P2 waits lgkmcnt(0); P3 runs from regs. Only P0's wait is exposed.
template<int EPI>
__global__ __launch_bounds__(512, 2) void gemm8(const u16* __restrict__ A,
    const u16* __restrict__ BT, int K, int ldc,
    u16* __restrict__ obf, float* __restrict__ ofp,
    const float* __restrict__ bcol, const float* __restrict__ brow){
  __shared__ __align__(16) u16 lsA[2 * 256 * 64];
  __shared__ __align__(16) u16 lsB[2 * 256 * 64];
  const int tid = threadIdx.x;
  const int lane = tid & 63;
  const int wave = tid >> 6;

  // bijective XCD swizzle (all grids here are %8==0)
  const u32 gx = gridDim.x;
  const u32 nwg = gx * gridDim.y;
  const u32 orig = blockIdx.y * gx + blockIdx.x;
  const u32 swzid = (orig & 7) * (nwg >> 3) + (orig >> 3);
  const int br = (int)(swzid / gx) * 256;
  const int bc = (int)(swzid % gx) * 256;

  const int wr  = (wave >> 2) * 128;   // wave row block
  const int wc_ = (wave & 3) * 64;     // wave col block

  // ds_read swizzled bases (true LDS byte offsets)
  const int fr = lane & 15;
  const int colb0 = (lane >> 4) * 16;
  const int swz = colb0 ^ ((fr & 7) << 4);
  const u32 baseA = lds_off(lsA);
  const u32 baseB = lds_off(lsB);
  const u32 sA0 = baseA + (u32)((wr + fr) * 128 + swz);
  const u32 sA1 = baseA + (u32)((wr + fr) * 128 + (swz ^ 64));
  const u32 sB0 = baseB + (u32)((wc_ + fr) * 128 + swz);
  const u32 sB1 = baseB + (u32)((wc_ + fr) * 128 + (swz ^ 64));

  // staging rounds: 512 thr x 16B = 8KB/round; 8 rounds/tile (4 A + 4 B).
  // linear LDS dst + inverse-swizzled global src (rule #21).
  const int r = tid >> 3, s = tid & 7;
  const int lc8 = ((s ^ (r & 7)) * 8);
  const int rb_ = (r & 31) + ((r >> 5) << 6);
  const int rA[4] = { r, r + 128, r + 64, r + 192 };       // A0:0-63 A1:128-191 A2:64-127 A3:192-255
  const int rB[4] = { rb_, rb_ + 128, rb_ + 32, rb_ + 160 };
  u32 srcA[4], srcB[4], dstA[4], dstB[4];
  #pragma unroll
  for (int i = 0; i < 4; i++){
    srcA[i] = (u32)(br + rA[i]) * (u32)K + (u32)lc8;
    srcB[i] = (u32)(bc + rB[i]) * (u32)K + (u32)lc8;
    dstA[i] = (u32)(rA[i] * 128 + s * 16);
    dstB[i] = (u32)(rB[i] * 128 + s * 16);
  }
  auto stA = [&](int i, u32 koff, u32 qb){ gload16(A  + srcA[i] + koff, (char*)lsA + qb + dstA[i]); };
  auto stB = [&](int i, u32 koff, u32 qb){ gload16(BT + srcB[i] + koff, (char*)lsB + qb + dstB[i]); };

  const int NT = K >> 6;
  f32x4 acc[8][4] = {};

  auto tile_body = [&](int t, auto W0_, auto W3_, auto BAR1_, auto ST0_, auto STR_){
    constexpr int  W0   = decltype(W0_)::v;
    constexpr int  W3   = decltype(W3_)::v;
    constexpr bool BAR1 = decltype(BAR1_)::v;
    constexpr bool ST0  = decltype(ST0_)::v;
    constexpr bool STR  = decltype(STR_)::v;
    const u32 pb = (t & 1) ? 32768u : 0u;
    const u32 qb = pb ^ 32768u;
    const u32 k1 = (u32)(t + 1) << 6;
    const u32 k2 = (u32)(t + 2) << 6;
    const u32 aA0 = sA0 + pb, aA1 = sA1 + pb, bB0 = sB0 + pb, bB1 = sB1 + pb;
    s16x8 a0[4][2], a1[4][2], b0[2][2], b1[2][2];

    // ---- P0: stage {A2,A3}(t+1)->qb; issue a0(8)+b0(4)+b1(4); wait 12; MFMA Q00
    if constexpr (ST0){ stA(2, k1, qb); stA(3, k1, qb); }
    a0[0][0] = dsr<0>(aA0);    a0[0][1] = dsr<0>(aA1);
    a0[1][0] = dsr<2048>(aA0); a0[1][1] = dsr<2048>(aA1);
    a0[2][0] = dsr<4096>(aA0); a0[2][1] = dsr<4096>(aA1);
    a0[3][0] = dsr<6144>(aA0); a0[3][1] = dsr<6144>(aA1);
    b0[0][0] = dsr<0>(bB0);    b0[0][1] = dsr<0>(bB1);
    b0[1][0] = dsr<2048>(bB0); b0[1][1] = dsr<2048>(bB1);
    b1[0][0] = dsr<4096>(bB0); b1[0][1] = dsr<4096>(bB1);
    b1[1][0] = dsr<6144>(bB0); b1[1][1] = dsr<6144>(bB1);
    lgw<4>();                       // a0,b0 ready; b1 in flight under Q00
    __builtin_amdgcn_sched_barrier(0);
    __builtin_amdgcn_s_setprio(1);
    #pragma unroll
    for (int kk = 0; kk < 2; kk++)
      #pragma unroll
      for (int m = 0; m < 4; m++)
        #pragma unroll
        for (int n = 0; n < 2; n++)
          acc[m][n] = __builtin_amdgcn_mfma_f32_16x16x32_bf16(a0[m][kk], b0[n][kk], acc[m][n], 0, 0, 0);
    __builtin_amdgcn_s_setprio(0);
    vmw<W0>();                      // retire A23(t): publishes it for P1's a1 reads
    __builtin_amdgcn_sched_barrier(0);
    __builtin_amdgcn_s_barrier();
    __builtin_amdgcn_sched_barrier(0);

    // ---- P1: stage {A0,A1}(t+2)->pb; issue a1(8); wait b1; MFMA Q01
    if constexpr (STR){ stA(0, k2, pb); stA(1, k2, pb); }
    a1[0][0] = dsr<8192>(aA0);  a1[0][1] = dsr<8192>(aA1);
    a1[1][0] = dsr<10240>(aA0); a1[1][1] = dsr<10240>(aA1);
    a1[2][0] = dsr<12288>(aA0); a1[2][1] = dsr<12288>(aA1);
    a1[3][0] = dsr<14336>(aA0); a1[3][1] = dsr<14336>(aA1);
    lgw<8>();                       // b1 ready; a1 in flight under Q01
    __builtin_amdgcn_sched_barrier(0);
    __builtin_amdgcn_s_setprio(1);
    #pragma unroll
    for (int kk = 0; kk < 2; kk++)
      #pragma unroll
      for (int m = 0; m < 4; m++)
        #pragma unroll
        for (int n = 0; n < 2; n++)
          acc[m][n + 2] = __builtin_amdgcn_mfma_f32_16x16x32_bf16(a0[m][kk], b1[n][kk], acc[m][n + 2], 0, 0, 0);
    __builtin_amdgcn_s_setprio(0);
    if constexpr (BAR1){            // guards P3's B23 overwrite (b1 reads done block-wide)
      __builtin_amdgcn_sched_barrier(0);
      __builtin_amdgcn_s_barrier();
      __builtin_amdgcn_sched_barrier(0);
    }

    // ---- P2: stage {B0,B1}(t+2)->pb; wait a1; MFMA Q11 (no barrier after)
    if constexpr (STR){ stB(0, k2, pb); stB(1, k2, pb); }
    lgw<0>();
    __builtin_amdgcn_sched_barrier(0);
    __builtin_amdgcn_s_setprio(1);
    #pragma unroll
    for (int kk = 0; kk < 2; kk++)
      #pragma unroll
      for (int m = 0; m < 4; m++)
        #pragma unroll
        for (int n = 0; n < 2; n++)
          acc[m + 4][n + 2] = __builtin_amdgcn_mfma_f32_16x16x32_bf16(a1[m][kk], b1[n][kk], acc[m + 4][n + 2], 0, 0, 0);
    __builtin_amdgcn_s_setprio(0);
    __builtin_amdgcn_sched_barrier(0);

    // ---- P3: stage {B2,B3}(t+2)->pb; MFMA Q10 from regs; boundary publish
    if constexpr (STR){ stB(2, k2, pb); stB(3, k2, pb); }
    __builtin_amdgcn_s_setprio(1);
    #pragma unroll
    for (int kk = 0; kk < 2; kk++)
      #pragma unroll
      for (int m = 0; m < 4; m++)
        #pragma unroll
        for (int n = 0; n < 2; n++)
          acc[m + 4][n] = __builtin_amdgcn_mfma_f32_16x16x32_bf16(a1[m][kk], b0[n][kk], acc[m + 4][n], 0, 0, 0);
    __builtin_amdgcn_s_setprio(0);
    if constexpr (W3 >= 0){
      vmw<W3>();                    // retire through B23(t+1): next tile's P0 reads
      __builtin_amdgcn_sched_barrier(0);
      __builtin_amdgcn_s_barrier();
      __builtin_amdgcn_sched_barrier(0);
    }
  };

  // prologue: tile0 all 8 rounds + tile1 first 6 rounds (consumption order)
  stA(0, 0, 0); stA(1, 0, 0); stB(0, 0, 0); stB(1, 0, 0);
  stB(2, 0, 0); stB(3, 0, 0); stA(2, 0, 0); stA(3, 0, 0);
  stA(0, 64, 32768u); stA(1, 64, 32768u); stB(0, 64, 32768u); stB(1, 64, 32768u);
  stB(2, 64, 32768u); stB(3, 64, 32768u);
  vmw<8>();
  __builtin_amdgcn_sched_barrier(0);
  __builtin_amdgcn_s_barrier();
  __builtin_amdgcn_sched_barrier(0);

  for (int t = 0; t < NT - 2; ++t)
    tile_body(t, icv<8>{}, icv<8>{}, bcv<true>{}, bcv<true>{}, bcv<true>{});
  tile_body(NT - 2, icv<8>{}, icv<2>{},  bcv<false>{}, bcv<true>{},  bcv<false>{});
  tile_body(NT - 1, icv<0>{}, icv<-1>{}, bcv<false>{}, bcv<false>{}, bcv<false>{});

  // epilogue
  const int orow0 = br + wr + ((lane >> 4) * 4);
  const int ocol0 = bc + wc_ + (lane & 15);
  #pragma unroll
  for (int m = 0; m < 8; m++){
    #pragma unroll
    for (int n = 0; n < 4; n++){
      #pragma unroll
      for (int rr = 0; rr < 4; rr++){
        int gr = orow0 + m * 16 + rr;
        int gc = ocol0 + n * 16;
        float v = acc[m][n][rr];
        size_t idx = (size_t)gr * ldc + gc;
        if (EPI == EPI_SBIAS)      obf[idx] = f2bf(v + 0.5f * brow[gr]);
        else if (EPI == EPI_GELU)  obf[idx] = f2bf(gelu_exact(v + bcol[gc]));
        else if (EPI == EPI_F32)   ofp[idx] = v;
        else                       ofp[idx] += v;
      }
    }
  }
}

// ---------- launch ----------
extern "C" void kernel_launch(void* const* d_in, const int* in_sizes, int n_in,
                              void* d_out, int out_size, void* d_ws, size_t ws_size,
                              hipStream_t stream){
  const float* x      = (const float*)d_in[0];
  const float* HpreR  = (const float*)d_in[1];
  const float* HpostR = (const float*)d_in[2];
  const float* HresR  = (const float*)d_in[3];
  const float* W1     = (const float*)d_in[4];
  const float* b1     = (const float*)d_in[5];
  const float* W2     = (const float*)d_in[6];
  const float* b2     = (const float*)d_in[7];
  const float* gpre   = (const float*)d_in[8];
  const float* bpre   = (const float*)d_in[9];
  const float* gpost  = (const float*)d_in[10];
  const float* bpost  = (const float*)d_in[11];
  float* out = (float*)d_out;
  char* w = (char*)d_ws;
  constexpr size_t MBc = 1ull << 20;

  u16*   W1T    = (u16*)(w + 0);          // [8192][4096] 64MB
  u16*   W2T    = (u16*)(w + 64 * MBc);   // [4096][8192] 64MB
  u16*   DPRET  = (u16*)(w + 128 * MBc);  // [4096][1024] 8MB  = (sigmoid(Hpre)-0.5)^T
  u16*   DPOSTT = (u16*)(w + 136 * MBc);  // [1024][4096] 8MB  = (2sigmoid(Hpost)-1)^T
  u16*   HREST  = (u16*)(w + 144 * MBc);  // [1024][1024] 2MB
  u16*   XN     = (u16*)(w + 146 * MBc);  // [8192][1024] 16MB
  u16*   XBF    = (u16*)(w + 162 * MBc);  // [8192][1024] 16MB
  float* S      = (float*)(w + 178 * MBc);// [8192]
  float* A0     = (float*)(w + 179 * MBc);// [1024][1024] fp32 4MB
  float* A0T    = (float*)(w + 183 * MBc);// 4MB
  float* Rv     = (float*)(w + 187 * MBc);// [1024]
  float* Cv     = Rv + 1024;              // [1024]
  u16*   XEXP   = (u16*)(w + 188 * MBc);  // [8192][4096] 64MB (reused chunkwise as h2)
  u16*   H1     = (u16*)(w + 252 * MBc);  // [Mc][8192] bf16 chunk buffer
  float* VAR    = (float*)(w + 252 * MBc);// [8192][1024] fp32 32MB (after H1 dead)

  const int Mc = (ws_size >= (316ull << 20)) ? 4096 : 2048;
  const int nch = 8192 / Mc;

  dim3 blk(256);

  // weight precompute (transposed to [N][K] for the B^T GEMM)
  transpose_op<OPC_CAST,  u16><<<dim3(128, 64), blk, 0, stream>>>(W1, W1T, 4096, 8192);
  transpose_op<OPC_CAST,  u16><<<dim3(64, 128), blk, 0, stream>>>(W2, W2T, 8192, 4096);
  transpose_op<OPC_SIGM05,u16><<<dim3(64, 16),  blk, 0, stream>>>(HpreR, DPRET, 1024, 4096);
  transpose_op<OPC_SIG2M1,u16><<<dim3(16, 64),  blk, 0, stream>>>(HpostR, DPOSTT, 4096, 1024);

  // sinkhorn (scaling-vector form; exact incl. eps placement)
  sk_softmax_k<<<1024, blk, 0, stream>>>(HresR, A0);
  transpose_op<OPC_CAST, float><<<dim3(16, 16), blk, 0, stream>>>(A0, A0T, 1024, 1024);
  sk_init<<<8, blk, 0, stream>>>(Rv, 2048);
  for (int i = 0; i < 20; i++){
    sk_pass<<<1024, blk, 0, stream>>>(A0,  Cv, Rv);   // row normalize
    sk_pass<<<1024, blk, 0, stream>>>(A0T, Rv, Cv);   // col normalize
  }
  sk_mat<<<1024, blk, 0, stream>>>(A0T, Rv, Cv, HREST);

  // pre-LN (+ fp32 row sums of xn, + bf16 copy of raw x)
  ln1_kernel<<<8192, blk, 0, stream>>>(x, gpre, bpre, XN, XBF, S);

  // G1: x_exp = xn @ (Hpre-0.5) + 0.5*s -> bf16 [8192][4096]
  gemm8<EPI_SBIAS><<<dim3(16, 32), dim3(512), 0, stream>>>(XN, DPRET, 1024, 4096,
                                                           XEXP, nullptr, nullptr, S);
  // G2/G3 in Mc-row chunks (h1 chunk buffer; h2 overwrites x_exp chunk)
  for (int c0 = 0; c0 < nch; c0++){
    const u16* ax = XEXP + (size_t)c0 * Mc * 4096;
    u16* h2c      = XEXP + (size_t)c0 * Mc * 4096;
    gemm8<EPI_GELU><<<dim3(32, Mc / 256), dim3(512), 0, stream>>>(ax, W1T, 4096, 8192,
                                                                  H1, nullptr, b1, nullptr);
    gemm8<EPI_GELU><<<dim3(16, Mc / 256), dim3(512), 0, stream>>>(H1, W2T, 8192, 4096,
                                                                  h2c, nullptr, b2, nullptr);
  }
  // G4: var = h2 @ (2sigmoid(Hpost)-1)   (rank-1 rowsum constant cancels in final LN)
  gemm8<EPI_F32><<<dim3(4, 32), dim3(512), 0, stream>>>(XEXP, DPOSTT, 4096, 1024,
                                                        nullptr, VAR, nullptr, nullptr);
  // G5: VAR += x @ Hres
  gemm8<EPI_ADDF32><<<dim3(4, 32), dim3(512), 0, stream>>>(XBF, HREST, 1024, 1024,
                                                           nullptr, VAR, nullptr, nullptr);
  // final LN -> fp32 out
  ln2_kernel<<<8192, blk, 0, stream>>>(VAR, gpost, bpost, out);
}